// Round 22
// baseline (104.283 us; speedup 1.0000x reference)
//
#include <hip/hip_runtime.h>
#include <hip/hip_bf16.h>
#include <math.h>

typedef __attribute__((ext_vector_type(8))) short bf16x8;
typedef __attribute__((ext_vector_type(4))) float f32x4;
typedef __attribute__((ext_vector_type(8))) _Float16 h8;
typedef unsigned long long u64;

#define NSAMP  128000
#define TFR    501
#define TP     512         // padded t-stride of power planes
#define FPOW   257
#define NF     257
#define B_SZ   64
#define CHUNKT 32
#define NCH    16
#define EPS_F  1.1920928955078125e-07f

#define ASEGB    65536     // A tile: 64 frames x 1024B ([s_e 512B | s_o 512B])
#define XFSTRIDE 524288    // per-sb folded bytes: 512 frames x 1024B
#define BGRPB    131072    // basis per parity group: 8ph x 16colgrp x 1024B
#define BPHB2    16384     // basis per phase per group

// ---- fused prep: fold-prepass (8192 blocks) + basis build (512 blocks) ---
// Fold: s_e[m] = w[m]x[m] + w[m+256]x[m+256], s_o = difference, per frame.
// Window w[n]=sin(pi n/512) via 1 sincos + angle-addition consts.
// Basis [grp(2)][ph(8)][colgrp(16)][lane(64)][8bf16] (r17 mapping, verbatim):
// grp0: bin=2*eo vs s_e (cc=16 dead-im hosts Nyquist (-1)^m); grp1: 2*eo+1.
__global__ __launch_bounds__(256)
void prep(const float* __restrict__ sig, const float* __restrict__ intf,
          unsigned short* __restrict__ Bt, unsigned short* __restrict__ xf)
{
    const int bid = blockIdx.x;
    if (bid < 8192) {
        const int sb = bid >> 6;
        const int frame = (bid & 63) * 8 + (threadIdx.x >> 5);
        const int m = (threadIdx.x & 31) * 8;
        const float* x = ((sb >> 6) ? sig : intf) + (size_t)(sb & 63) * NSAMP;
        const int t = min(frame, TFR - 1);
        const int p0 = t * 256 + m - 256;
        float xa[8], xb[8];
        if (p0 >= 0 && p0 + 264 <= NSAMP) {
            float4 a0 = *(const float4*)(x + p0);
            float4 a1 = *(const float4*)(x + p0 + 4);
            float4 b0 = *(const float4*)(x + p0 + 256);
            float4 b1 = *(const float4*)(x + p0 + 260);
            xa[0]=a0.x; xa[1]=a0.y; xa[2]=a0.z; xa[3]=a0.w;
            xa[4]=a1.x; xa[5]=a1.y; xa[6]=a1.z; xa[7]=a1.w;
            xb[0]=b0.x; xb[1]=b0.y; xb[2]=b0.z; xb[3]=b0.w;
            xb[4]=b1.x; xb[5]=b1.y; xb[6]=b1.z; xb[7]=b1.w;
        } else {
            #pragma unroll
            for (int e = 0; e < 8; ++e) {
                int p = p0 + e;
                if (p < 0) p = -p;
                if (p >= NSAMP) p = 2 * NSAMP - 2 - p;
                xa[e] = x[p];
                int q = p0 + 256 + e;
                if (q >= NSAMP) q = 2 * NSAMP - 2 - q;
                xb[e] = x[q];
            }
        }
        // w[m+e] = s*C[e]+c*S[e];  w[m+256+e] = c*C[e]-s*S[e]
        const float CT[8] = {1.0f, 0.99998118f, 0.99992470f, 0.99983058f,
                             0.99969882f, 0.99952942f, 0.99932238f, 0.99907773f};
        const float ST[8] = {0.0f, 0.00613588f, 0.01227154f, 0.01840673f,
                             0.02454123f, 0.03067480f, 0.03680722f, 0.04293826f};
        float th = (float)m * (float)(M_PI / 512.0);
        float s_ = sinf(th), c_ = cosf(th);
        unsigned short he[8], ho[8];
        #pragma unroll
        for (int e = 0; e < 8; ++e) {
            float we = s_ * CT[e] + c_ * ST[e];
            float wo = c_ * CT[e] - s_ * ST[e];
            float pa = xa[e] * we;
            float pb = xb[e] * wo;
            __hip_bfloat16 t0 = __float2bfloat16(pa + pb);
            __hip_bfloat16 t1 = __float2bfloat16(pa - pb);
            he[e] = *(unsigned short*)&t0;
            ho[e] = *(unsigned short*)&t1;
        }
        char* op = (char*)xf + (size_t)sb * XFSTRIDE + frame * 1024 + m * 2;
        *(ulonglong2*)op = make_ulonglong2(
            (u64)he[0]|((u64)he[1]<<16)|((u64)he[2]<<32)|((u64)he[3]<<48),
            (u64)he[4]|((u64)he[5]<<16)|((u64)he[6]<<32)|((u64)he[7]<<48));
        *(ulonglong2*)(op + 512) = make_ulonglong2(
            (u64)ho[0]|((u64)ho[1]<<16)|((u64)ho[2]<<32)|((u64)ho[3]<<48),
            (u64)ho[4]|((u64)ho[5]<<16)|((u64)ho[6]<<32)|((u64)ho[7]<<48));
    } else {
        const int c = bid - 8192;            // 0..511
        const int grp = c >> 8, cc = c & 255;
        const int eo = (cc >> 5) * 16 + (cc & 15);
        const int isIm = (cc >> 4) & 1;
        const int bin = grp ? (2 * eo + 1) : (2 * eo);
        const int m = threadIdx.x;           // 0..255
        float v;
        if (grp == 0 && cc == 16) {
            v = (m & 1) ? -1.f : 1.f;        // Nyquist basis vs s_e
        } else {
            int mm = (bin * m) & 511;
            float th = (float)mm * (float)(2.0 * M_PI / 512.0);
            v = isIm ? -sinf(th) : cosf(th);
        }
        __hip_bfloat16 h = __float2bfloat16(v);
        int ph = m >> 5, cg16 = cc >> 4;
        int lane = ((m >> 3) & 3) * 16 + (cc & 15);
        size_t idx = (((size_t)(grp * 8 + ph) * 16 + cg16) * 64 + lane) * 8 + (m & 7);
        Bt[idx] = *reinterpret_cast<unsigned short*>(&h);
    }
}

// ---- MFMA DFT GEMM v22: folded K=256, DMA A-stage, barrier-free ---------
// grid (8 mchunk, 64 b, 2 s) = 1024 blocks, block 512 (8 waves).
// Waves 0..3 even bins (s_e half of A), 4..7 odd bins (s_o half).
// A: 64KB folded frames via 8x global_load_lds(16B)/thread, pre-swz source
// (involution on bits 10-12 -> 4-6). 8 phases of K=32; B from L2 to regs,
// copy-free ping-pong. MFMA count HALF of r21.
__global__ __launch_bounds__(512)
void dft_gemm(const unsigned short* __restrict__ xf,
              const unsigned short* __restrict__ Bt,
              _Float16* __restrict__ powo)
{
    __shared__ char As[ASEGB];

    const int mchunk = blockIdx.x, b = blockIdx.y, s = blockIdx.z;
    const int tid = threadIdx.x, lane = tid & 63, wn = tid >> 6;  // 8 waves
    const int lq = lane >> 4, ll = lane & 15;
    const int sb = s * 64 + b;

    // ---- A staging: pure DMA, swizzle on the SOURCE address ----
    {
        const char* xg = (const char*)xf + (size_t)sb * XFSTRIDE
                       + (size_t)mchunk * ASEGB;
        #pragma unroll
        for (int r = 0; r < 8; ++r) {
            int o = r * 8192 + tid * 16;
            int src = o ^ (((o >> 10) & 7) << 4);
            __builtin_amdgcn_global_load_lds(
                (const __attribute__((address_space(1))) void*)(xg + src),
                (__attribute__((address_space(3))) void*)(As + o), 16, 0, 0);
        }
    }

    const int grp = wn >> 2;            // 0: even bins (s_e), 1: odd (s_o)
    const int grpoff = grp * 512;       // byte offset into A row
    const char* WB = (const char*)Bt + (size_t)grp * BGRPB
                   + (wn & 3) * 4096 + lane * 16;

    bf16x8 B0[4], B1[4];

    auto loadPh = [&](int ph, bf16x8 (&dst)[4]) {
        const char* bp = WB + (size_t)ph * BPHB2;
        #pragma unroll
        for (int nf = 0; nf < 4; ++nf)
            dst[nf] = *(const bf16x8*)(bp + nf * 1024);
    };

    loadPh(0, B0);
    asm volatile("s_waitcnt vmcnt(0)" ::: "memory");   // A + B0 landed
    __syncthreads();                                   // the ONLY barrier

    f32x4 acc[4][4];
    #pragma unroll
    for (int i = 0; i < 4; ++i)
        #pragma unroll
        for (int j = 0; j < 4; ++j) acc[i][j] = 0;

    auto doPhase = [&](int ph, bf16x8 (&cur)[4]) {
        bf16x8 af[4];
        #pragma unroll
        for (int mf = 0; mf < 4; ++mf) {
            int a = (mf * 16 + ll) * 1024 + grpoff + ph * 64 + lq * 16;
            a ^= ((a >> 10) & 7) << 4;
            af[mf] = *(const bf16x8*)(As + a);
        }
        __builtin_amdgcn_s_setprio(1);
        #pragma unroll
        for (int mf = 0; mf < 4; ++mf)
            #pragma unroll
            for (int nf = 0; nf < 4; ++nf)
                acc[mf][nf] = __builtin_amdgcn_mfma_f32_16x16x32_bf16(
                    af[mf], cur[nf], acc[mf][nf], 0, 0, 0);
        __builtin_amdgcn_s_setprio(0);
    };

    #pragma unroll 1
    for (int pp2 = 0; pp2 < 4; ++pp2) {
        const int ph = pp2 * 2;
        loadPh(ph + 1, B1);                 // prefetch odd phase
        doPhase(ph, B0);                    // compute even phase
        if (pp2 < 3) loadPh(ph + 2, B0);    // prefetch next even phase
        doPhase(ph + 1, B1);                // compute odd phase
    }

    // ---- epilogue: power, t-major fp16, packed u64 (pad rows absorb tail) --
    _Float16* pbase = powo + (size_t)sb * FPOW * TP;
    #pragma unroll
    for (int mf = 0; mf < 4; ++mf) {
        const int rl0 = mchunk * 64 + mf * 16 + lq * 4;
        #pragma unroll
        for (int p = 0; p < 2; ++p) {
            f32x4 re = acc[mf][2 * p], im = acc[mf][2 * p + 1];
            int gb = (wn & 3) * 2 + p;
            int eo = gb * 16 + ll;
            int bin = grp ? (2 * eo + 1) : (2 * eo);
            bool nyq = (grp == 0) && (gb == 0) && (ll == 0);
            unsigned short hp[4], hn[4];
            #pragma unroll
            for (int j = 0; j < 4; ++j) {
                float pr = re[j] * re[j];
                float pi = im[j] * im[j];
                _Float16 hv = (_Float16)(nyq ? pr : (pr + pi));
                hp[j] = *(unsigned short*)&hv;
                _Float16 hw = (_Float16)pi;
                hn[j] = *(unsigned short*)&hw;
            }
            u64 pk = (u64)hp[0] | ((u64)hp[1] << 16) |
                     ((u64)hp[2] << 32) | ((u64)hp[3] << 48);
            *(u64*)(pbase + (size_t)bin * TP + rl0) = pk;
            if (nyq) {
                u64 pk2 = (u64)hn[0] | ((u64)hn[1] << 16) |
                          ((u64)hn[2] << 32) | ((u64)hn[3] << 48);
                *(u64*)(pbase + (size_t)256 * TP + rl0) = pk2;
            }
        }
    }
}

// ---- warm-up: vectorized fp16 loads, static indexing --------------------
template<int W>
__device__ __forceinline__ float warm_fixed(const _Float16* __restrict__ nrow,
                                            int base, float alpha, float oma) {
    h8 blk[W / 8];
    #pragma unroll
    for (int i = 0; i < W / 8; ++i)
        blk[i] = *(const h8*)(nrow + base + i * 8);
    float v = (float)blk[0][0];
    #pragma unroll
    for (int i = 1; i < W; ++i)
        v = fmaf(alpha, v, oma * (float)blk[i / 8][i % 8]);
    v = fmaf(alpha, v, oma * (float)nrow[base + W]);
    return v;
}

// ---- chunked IIR scan + SPP + MSE, t-major fp16 planes ------------------
__global__ __launch_bounds__(256, 4)
void spp_loss_kernel(const _Float16* __restrict__ noiseP,
                     const _Float16* __restrict__ noisyP,
                     const float* __restrict__ est,
                     float* __restrict__ out,
                     float alpha)
{
    const double XI = 31.622776601683793;
    const float RATIO = (float)(1.0 + XI);
    const float COEF  = (float)(XI / (1.0 + XI));
    const float INVN  = (float)(1.0 / ((double)B_SZ * NF * TFR));

    int tid = blockIdx.x * blockDim.x + threadIdx.x;
    int f   = tid % NF;
    int rem = tid / NF;
    int c   = rem & (NCH - 1);
    int b   = rem >> 4;

    float local = 0.f;
    if (b < B_SZ) {
        const int t0   = c * CHUNKT;
        const int tend = min(TFR, t0 + CHUNKT);
        const _Float16* nrow = noiseP + ((size_t)b * NF + f) * TP;
        const _Float16* yrow = noisyP + ((size_t)b * NF + f) * TP;
        const float* erow = est + ((size_t)b * NF + f) * TFR;
        const float oma = 1.f - alpha;

        float v;
        if (t0 == 0)            v = (float)nrow[0];
        else if (t0 == CHUNKT)  v = warm_fixed<32>(nrow, 0, alpha, oma);
        else                    v = warm_fixed<48>(nrow, t0 - 48, alpha, oma);

        h8 wn8[4], wy8[4];
        #pragma unroll
        for (int i = 0; i < 4; ++i) {
            wn8[i] = *(const h8*)(nrow + t0 + i * 8);
            wy8[i] = *(const h8*)(yrow + t0 + i * 8);
        }
        float last_n = (float)nrow[t0 + 32];
        float last_y = (float)yrow[t0 + 32];
        float qe[32];
        #pragma unroll
        for (int i = 0; i < 32; ++i)
            qe[i] = erow[min(t0 + 1 + i, TFR - 1)];

        {
            float np = (float)wy8[0][0];
            float e0 = erow[t0];
            float expo = -np / (v + EPS_F) * COEF;
            float spp  = 1.f / fmaf(RATIO, __expf(expo), 1.f);
            float d = e0 - spp;
            local = fmaf(d, d, local);
        }
        #pragma unroll
        for (int i = 0; i < 32; ++i) {
            int t = t0 + 1 + i;
            float nv = (i < 31) ? (float)wn8[(i + 1) / 8][(i + 1) % 8] : last_n;
            v = fmaf(alpha, v, oma * nv);
            if (t < tend) {
                float yv = (i < 31) ? (float)wy8[(i + 1) / 8][(i + 1) % 8] : last_y;
                float expo = -yv / (v + EPS_F) * COEF;
                float spp  = 1.f / fmaf(RATIO, __expf(expo), 1.f);
                float d = qe[i] - spp;
                local = fmaf(d, d, local);
            }
        }
    }

    for (int off = 32; off > 0; off >>= 1)
        local += __shfl_down(local, off);
    __shared__ float wsum[4];
    if ((threadIdx.x & 63) == 0) wsum[threadIdx.x >> 6] = local;
    __syncthreads();
    if (threadIdx.x == 0) {
        float ssum = (wsum[0] + wsum[1]) + (wsum[2] + wsum[3]);
        atomicAdd(out, ssum * INVN);
    }
}

extern "C" void kernel_launch(void* const* d_in, const int* in_sizes, int n_in,
                              void* d_out, int out_size, void* d_ws, size_t ws_size,
                              hipStream_t stream) {
    const float* est  = (const float*)d_in[0];   // spp_estimate (B,1,F,T)
    const float* sig  = (const float*)d_in[1];   // input_sig    (B,1,N)
    const float* intf = (const float*)d_in[2];   // interference (B,1,N)

    unsigned short* Bt = (unsigned short*)d_ws;                       // 256 KB
    unsigned short* xf = (unsigned short*)((char*)d_ws + (size_t)512 * 1024);
    _Float16* powp = (_Float16*)((char*)d_ws + (size_t)512 * 1024
                                 + (size_t)128 * XFSTRIDE);

    hipLaunchKernelGGL(prep, dim3(8192 + 512), dim3(256), 0, stream,
                       sig, intf, Bt, xf);
    hipMemsetAsync(d_out, 0, sizeof(float), stream);

    dim3 gG(8, 64, 2);
    hipLaunchKernelGGL(dft_gemm, gG, dim3(512), 0, stream, xf, Bt, powp);

    const double alpha_d = exp(-((double)256) / (16000.0 * 0.072));
    const _Float16* noiseP = powp;                            // sb 0..63
    const _Float16* noisyP = powp + (size_t)B_SZ * FPOW * TP; // sb 64..127
    dim3 gB((B_SZ * NCH * NF + 255) / 256);
    hipLaunchKernelGGL(spp_loss_kernel, gB, dim3(256), 0, stream,
                       noiseP, noisyP, est, (float*)d_out, (float)alpha_d);
}

// Round 23
// 92.534 us; speedup vs baseline: 1.1270x; 1.1270x over previous
//
#include <hip/hip_runtime.h>
#include <hip/hip_bf16.h>
#include <math.h>

typedef __attribute__((ext_vector_type(8))) short bf16x8;
typedef __attribute__((ext_vector_type(4))) float f32x4;
typedef __attribute__((ext_vector_type(8))) _Float16 h8;
typedef unsigned long long u64;

#define NSAMP  128000
#define TFR    501
#define TP     512         // padded t-stride of power planes
#define FPOW   257
#define NF     257
#define B_SZ   64
#define CHUNKT 32
#define NCH    16
#define EPS_F  1.1920928955078125e-07f

#define SEG    16640       // 64*256 + 256 samples per 64-frame chunk
#define ASEGB  66560       // SEG * 4 bytes (f32 in LDS)
#define BPHB   32768       // one K=32 phase of basis: 512 cols = 32 KB

// ---- basis, layout [ph(16)][colgrp(32)][lane(64)][8 bf16] ---------------
__global__ __launch_bounds__(256)
void build_basis(unsigned short* __restrict__ Bt) {
    int col = blockIdx.x;
    int g = col >> 5, o = col & 15;
    int isIm = (col >> 4) & 1;
    int bin = g * 16 + o;
    for (int k = threadIdx.x; k < 512; k += 256) {
        float w = sinf((float)k * (float)(M_PI / 512.0));   // sqrt-hann
        float v;
        if (col == 16) {
            v = w * ((k & 1) ? -1.f : 1.f);
        } else {
            int mm = (bin * k) & 511;
            float th = (float)mm * (float)(2.0 * M_PI / 512.0);
            v = w * (isIm ? -sinf(th) : cosf(th));
        }
        __hip_bfloat16 h = __float2bfloat16(v);
        int ph = k >> 5, kq = (k >> 3) & 3, j = k & 7;
        size_t idx = (((size_t)ph * 32 + (col >> 4)) * 64
                      + kq * 16 + (col & 15)) * 8 + j;
        Bt[idx] = *reinterpret_cast<unsigned short*>(&h);
    }
}

// ---- MFMA DFT GEMM v23: raw-f32 DMA A-stage, in-loop cvt ----------------
// grid (8 mchunk, 64 b, 2 s) = 1024 blocks, block 512 (8 waves, 1M x 8N).
// A: raw f32 signal segment (66.5KB) in LDS. Interior chunks: pure
//    global_load_lds DMA with pre-swizzled source (bits 10-12 -> 4-6
//    involution; tail region identity). Edge chunks (0,7): VALU staging
//    with reflect. K-loop converts f32->bf16 in-register (hidden by MFMA).
// B: L2-resident basis -> regs, copy-free ping-pong (r15/r16 proven).
__global__ __launch_bounds__(512)
void dft_gemm(const float* __restrict__ sig,
              const float* __restrict__ intf,
              const unsigned short* __restrict__ Bt,
              _Float16* __restrict__ powo)
{
    extern __shared__ char As[];

    const int mchunk = blockIdx.x, b = blockIdx.y, s = blockIdx.z;
    const int tid = threadIdx.x, lane = tid & 63, wn = tid >> 6;  // 8 waves
    const int lq = lane >> 4, ll = lane & 15;
    const float* x = (s == 0 ? intf : sig) + (size_t)b * NSAMP;
    const int tbase = mchunk * 16384 - 256;

    // ---- A staging ----
    if (mchunk != 0 && mchunk != 7) {
        // pure DMA: LDS linear dest, source pre-swizzled (involution)
        const char* xg = (const char*)(x + tbase);
        #pragma unroll
        for (int r = 0; r < 8; ++r) {
            int o = r * 8192 + tid * 16;
            int src = o ^ (((o >> 10) & 7) << 4);
            __builtin_amdgcn_global_load_lds(
                (const __attribute__((address_space(1))) void*)(xg + src),
                (__attribute__((address_space(3))) void*)(As + o), 16, 0, 0);
        }
        if (tid < 64) {
            int o = 65536 + tid * 16;     // (o>>10)&7 == 0 here: identity
            __builtin_amdgcn_global_load_lds(
                (const __attribute__((address_space(1))) void*)(xg + o),
                (__attribute__((address_space(3))) void*)(As + o), 16, 0, 0);
        }
    } else {
        // edge: reflect-indexed VALU staging, swizzled float4 ds_writes
        const int jlo = (tbase < 0) ? -tbase : 0;
        const int jhi = (tbase + SEG > NSAMP) ? (NSAMP - tbase) : SEG;
        for (int i = tid; i < SEG / 4; i += 512) {
            int j = i * 4;
            float4 v;
            if (j >= jlo && j + 4 <= jhi) {
                v = *(const float4*)(x + tbase + j);
            } else {
                float f[4];
                #pragma unroll
                for (int e = 0; e < 4; ++e) {
                    int p = tbase + j + e;
                    if (p < 0) p = -p;
                    if (p >= NSAMP) p = 2 * NSAMP - 2 - p;
                    f[e] = x[p];
                }
                v = make_float4(f[0], f[1], f[2], f[3]);
            }
            int a = i * 16;
            a ^= ((a >> 10) & 7) << 4;
            *(float4*)(As + a) = v;
        }
    }

    // per-lane byte base into basis for this wave's 4 col-groups
    const char* bb = (const char*)Bt + (size_t)(wn * 4 * 64 + lane) * 16;

    bf16x8 B0[4], B1[4];

    auto loadPh = [&](int ph, bf16x8 (&dst)[4]) {
        const char* bp = bb + (size_t)ph * BPHB;
        #pragma unroll
        for (int nf = 0; nf < 4; ++nf)
            dst[nf] = *(const bf16x8*)(bp + nf * 1024);
    };

    loadPh(0, B0);
    asm volatile("s_waitcnt vmcnt(0)" ::: "memory");   // A-DMA + B0 landed
    __syncthreads();                                   // the ONLY barrier

    f32x4 acc[4][4];
    #pragma unroll
    for (int i = 0; i < 4; ++i)
        #pragma unroll
        for (int j = 0; j < 4; ++j) acc[i][j] = 0;

    auto doPhase = [&](int ph, bf16x8 (&cur)[4]) {
        bf16x8 af[4];
        #pragma unroll
        for (int mf = 0; mf < 4; ++mf) {
            // row = mf*16+ll (hop-dedup: row stride 256 samples = 1024B)
            int a0 = (mf * 16 + ll) * 1024 + ph * 128 + lq * 32;
            int a1 = a0 + 16;
            a0 ^= ((a0 >> 10) & 7) << 4;
            a1 ^= ((a1 >> 10) & 7) << 4;
            f32x4 v0 = *(const f32x4*)(As + a0);
            f32x4 v1 = *(const f32x4*)(As + a1);
            #pragma unroll
            for (int e = 0; e < 4; ++e) {
                __hip_bfloat16 h0 = __float2bfloat16(v0[e]);
                __hip_bfloat16 h1 = __float2bfloat16(v1[e]);
                af[mf][e]     = *reinterpret_cast<short*>(&h0);
                af[mf][e + 4] = *reinterpret_cast<short*>(&h1);
            }
        }
        __builtin_amdgcn_s_setprio(1);
        #pragma unroll
        for (int mf = 0; mf < 4; ++mf)
            #pragma unroll
            for (int nf = 0; nf < 4; ++nf)
                acc[mf][nf] = __builtin_amdgcn_mfma_f32_16x16x32_bf16(
                    af[mf], cur[nf], acc[mf][nf], 0, 0, 0);
        __builtin_amdgcn_s_setprio(0);
    };

    #pragma unroll 1
    for (int pp2 = 0; pp2 < 8; ++pp2) {
        const int ph = pp2 * 2;
        loadPh(ph + 1, B1);                 // prefetch odd phase
        doPhase(ph, B0);                    // compute even phase
        if (pp2 < 7) loadPh(ph + 2, B0);    // prefetch next even phase
        doPhase(ph + 1, B1);                // compute odd phase
    }

    // ---- epilogue: power = re^2 + im^2, t-major fp16, packed u64 stores ----
    const int sb = s * 64 + b;
    _Float16* pbase = powo + (size_t)sb * FPOW * TP;
    #pragma unroll
    for (int mf = 0; mf < 4; ++mf) {
        const int rl0 = mchunk * 64 + mf * 16 + lq * 4;
        #pragma unroll
        for (int p = 0; p < 2; ++p) {
            f32x4 re = acc[mf][2 * p], im = acc[mf][2 * p + 1];
            int gbin = wn * 2 + p;
            int bin = gbin * 16 + ll;
            bool nyq = (gbin == 0) && (ll == 0);
            unsigned short hp[4], hn[4];
            #pragma unroll
            for (int j = 0; j < 4; ++j) {
                float pr = re[j] * re[j];
                float pi = im[j] * im[j];
                _Float16 hv = (_Float16)(nyq ? pr : (pr + pi));
                hp[j] = *(unsigned short*)&hv;
                _Float16 hw = (_Float16)pi;
                hn[j] = *(unsigned short*)&hw;
            }
            u64 pk = (u64)hp[0] | ((u64)hp[1] << 16) |
                     ((u64)hp[2] << 32) | ((u64)hp[3] << 48);
            *(u64*)(pbase + (size_t)bin * TP + rl0) = pk;
            if (nyq) {
                u64 pk2 = (u64)hn[0] | ((u64)hn[1] << 16) |
                          ((u64)hn[2] << 32) | ((u64)hn[3] << 48);
                *(u64*)(pbase + (size_t)256 * TP + rl0) = pk2;
            }
        }
    }
}

// ---- warm-up: vectorized fp16 loads, static indexing --------------------
template<int W>
__device__ __forceinline__ float warm_fixed(const _Float16* __restrict__ nrow,
                                            int base, float alpha, float oma) {
    h8 blk[W / 8];
    #pragma unroll
    for (int i = 0; i < W / 8; ++i)
        blk[i] = *(const h8*)(nrow + base + i * 8);
    float v = (float)blk[0][0];
    #pragma unroll
    for (int i = 1; i < W; ++i)
        v = fmaf(alpha, v, oma * (float)blk[i / 8][i % 8]);
    v = fmaf(alpha, v, oma * (float)nrow[base + W]);
    return v;
}

// ---- chunked IIR scan + SPP + MSE, t-major fp16 planes ------------------
__global__ __launch_bounds__(256, 4)
void spp_loss_kernel(const _Float16* __restrict__ noiseP,
                     const _Float16* __restrict__ noisyP,
                     const float* __restrict__ est,
                     float* __restrict__ out,
                     float alpha)
{
    const double XI = 31.622776601683793;
    const float RATIO = (float)(1.0 + XI);
    const float COEF  = (float)(XI / (1.0 + XI));
    const float INVN  = (float)(1.0 / ((double)B_SZ * NF * TFR));

    int tid = blockIdx.x * blockDim.x + threadIdx.x;
    int f   = tid % NF;
    int rem = tid / NF;
    int c   = rem & (NCH - 1);
    int b   = rem >> 4;

    float local = 0.f;
    if (b < B_SZ) {
        const int t0   = c * CHUNKT;
        const int tend = min(TFR, t0 + CHUNKT);
        const _Float16* nrow = noiseP + ((size_t)b * NF + f) * TP;
        const _Float16* yrow = noisyP + ((size_t)b * NF + f) * TP;
        const float* erow = est + ((size_t)b * NF + f) * TFR;
        const float oma = 1.f - alpha;

        float v;
        if (t0 == 0)            v = (float)nrow[0];
        else if (t0 == CHUNKT)  v = warm_fixed<32>(nrow, 0, alpha, oma);
        else                    v = warm_fixed<48>(nrow, t0 - 48, alpha, oma);

        h8 wn8[4], wy8[4];
        #pragma unroll
        for (int i = 0; i < 4; ++i) {
            wn8[i] = *(const h8*)(nrow + t0 + i * 8);
            wy8[i] = *(const h8*)(yrow + t0 + i * 8);
        }
        float last_n = (float)nrow[t0 + 32];
        float last_y = (float)yrow[t0 + 32];
        float qe[32];
        #pragma unroll
        for (int i = 0; i < 32; ++i)
            qe[i] = erow[min(t0 + 1 + i, TFR - 1)];

        {
            float np = (float)wy8[0][0];
            float e0 = erow[t0];
            float expo = -np / (v + EPS_F) * COEF;
            float spp  = 1.f / fmaf(RATIO, __expf(expo), 1.f);
            float d = e0 - spp;
            local = fmaf(d, d, local);
        }
        #pragma unroll
        for (int i = 0; i < 32; ++i) {
            int t = t0 + 1 + i;
            float nv = (i < 31) ? (float)wn8[(i + 1) / 8][(i + 1) % 8] : last_n;
            v = fmaf(alpha, v, oma * nv);
            if (t < tend) {
                float yv = (i < 31) ? (float)wy8[(i + 1) / 8][(i + 1) % 8] : last_y;
                float expo = -yv / (v + EPS_F) * COEF;
                float spp  = 1.f / fmaf(RATIO, __expf(expo), 1.f);
                float d = qe[i] - spp;
                local = fmaf(d, d, local);
            }
        }
    }

    for (int off = 32; off > 0; off >>= 1)
        local += __shfl_down(local, off);
    __shared__ float wsum[4];
    if ((threadIdx.x & 63) == 0) wsum[threadIdx.x >> 6] = local;
    __syncthreads();
    if (threadIdx.x == 0) {
        float ssum = (wsum[0] + wsum[1]) + (wsum[2] + wsum[3]);
        atomicAdd(out, ssum * INVN);
    }
}

extern "C" void kernel_launch(void* const* d_in, const int* in_sizes, int n_in,
                              void* d_out, int out_size, void* d_ws, size_t ws_size,
                              hipStream_t stream) {
    const float* est  = (const float*)d_in[0];   // spp_estimate (B,1,F,T)
    const float* sig  = (const float*)d_in[1];   // input_sig    (B,1,N)
    const float* intf = (const float*)d_in[2];   // interference (B,1,N)

    unsigned short* Bt = (unsigned short*)d_ws;                 // 512 KB basis
    _Float16* powp = (_Float16*)((char*)d_ws + (size_t)512 * 1024);

    hipLaunchKernelGGL(build_basis, dim3(512), dim3(256), 0, stream, Bt);
    hipMemsetAsync(d_out, 0, sizeof(float), stream);

    hipFuncSetAttribute((const void*)dft_gemm,
                        hipFuncAttributeMaxDynamicSharedMemorySize, ASEGB);
    dim3 gG(8, 64, 2);
    hipLaunchKernelGGL(dft_gemm, gG, dim3(512), ASEGB, stream,
                       sig, intf, Bt, powp);

    const double alpha_d = exp(-((double)256) / (16000.0 * 0.072));
    const _Float16* noiseP = powp;                            // sb 0..63
    const _Float16* noisyP = powp + (size_t)B_SZ * FPOW * TP; // sb 64..127
    dim3 gB((B_SZ * NCH * NF + 255) / 256);
    hipLaunchKernelGGL(spp_loss_kernel, gB, dim3(256), 0, stream,
                       noiseP, noisyP, est, (float*)d_out, (float)alpha_d);
}

// Round 24
// 84.983 us; speedup vs baseline: 1.2271x; 1.0889x over previous
//
#include <hip/hip_runtime.h>
#include <hip/hip_bf16.h>
#include <math.h>

typedef __attribute__((ext_vector_type(8))) short bf16x8;
typedef __attribute__((ext_vector_type(4))) float f32x4;
typedef __attribute__((ext_vector_type(8))) _Float16 h8;
typedef unsigned long long u64;

#define NSAMP  128000
#define TFR    501
#define TP     512         // padded t-stride of power planes
#define FPOW   257
#define NF     257
#define B_SZ   64
#define CHUNKT 32
#define NCH    16
#define EPS_F  1.1920928955078125e-07f

#define SEG    16640       // 64*256 + 256 samples per 64-frame chunk
#define ASEGB  66560       // SEG * 4 bytes: f32 staging region (bf16 in front)
#define BPHB   32768       // one K=32 phase of basis: 512 cols = 32 KB

// ---- basis, layout [ph(16)][colgrp(32)][lane(64)][8 bf16] ---------------
__global__ __launch_bounds__(256)
void build_basis(unsigned short* __restrict__ Bt) {
    int col = blockIdx.x;
    int g = col >> 5, o = col & 15;
    int isIm = (col >> 4) & 1;
    int bin = g * 16 + o;
    for (int k = threadIdx.x; k < 512; k += 256) {
        float w = sinf((float)k * (float)(M_PI / 512.0));   // sqrt-hann
        float v;
        if (col == 16) {
            v = w * ((k & 1) ? -1.f : 1.f);
        } else {
            int mm = (bin * k) & 511;
            float th = (float)mm * (float)(2.0 * M_PI / 512.0);
            v = w * (isIm ? -sinf(th) : cosf(th));
        }
        __hip_bfloat16 h = __float2bfloat16(v);
        int ph = k >> 5, kq = (k >> 3) & 3, j = k & 7;
        size_t idx = (((size_t)ph * 32 + (col >> 4)) * 64
                      + kq * 16 + (col & 15)) * 8 + j;
        Bt[idx] = *reinterpret_cast<unsigned short*>(&h);
    }
}

// ---- MFMA DFT GEMM v24: f32 DMA -> in-LDS convert -> r16 K-loop ---------
// grid (8 mchunk, 64 b, 2 s) = 1024 blocks, block 512 (8 waves, 1M x 8N).
// Stage: raw f32 segment via global_load_lds (linear, clamped at edges);
// reflect handled by LDS->LDS mirror copies (disjoint ranges); one convert
// sweep (wave-contiguous b128 reads -> packed bf16 swizzled writes into the
// front 33KB). K-loop = r16's proven bf16 ping-pong, byte-for-byte.
__global__ __launch_bounds__(512)
void dft_gemm(const float* __restrict__ sig,
              const float* __restrict__ intf,
              const unsigned short* __restrict__ Bt,
              _Float16* __restrict__ powo)
{
    extern __shared__ char As[];

    const int mchunk = blockIdx.x, b = blockIdx.y, s = blockIdx.z;
    const int tid = threadIdx.x, lane = tid & 63, wn = tid >> 6;  // 8 waves
    const int lq = lane >> 4, ll = lane & 15;
    const float* x = (s == 0 ? intf : sig) + (size_t)b * NSAMP;
    const int tbase = mchunk * 16384 - 256;

    // ---- Step 1: f32 DMA into LDS (linear), edge-clamped ----
    if (mchunk >= 1 && mchunk <= 6) {
        const char* xg = (const char*)(x + tbase);
        #pragma unroll
        for (int r = 0; r < 8; ++r) {
            int o = r * 8192 + tid * 16;
            __builtin_amdgcn_global_load_lds(
                (const __attribute__((address_space(1))) void*)(xg + o),
                (__attribute__((address_space(3))) void*)(As + o), 16, 0, 0);
        }
        if (tid < 64) {
            int o = 65536 + tid * 16;
            __builtin_amdgcn_global_load_lds(
                (const __attribute__((address_space(1))) void*)(xg + o),
                (__attribute__((address_space(3))) void*)(As + o), 16, 0, 0);
        }
    } else if (mchunk == 0) {
        // dest [1024, 66560) <- x[0 ..), exactly 8 rounds
        const char* xg = (const char*)x;
        #pragma unroll
        for (int r = 0; r < 8; ++r) {
            int o = 1024 + r * 8192 + tid * 16;
            __builtin_amdgcn_global_load_lds(
                (const __attribute__((address_space(1))) void*)(xg + o - 1024),
                (__attribute__((address_space(3))) void*)(As + o), 16, 0, 0);
        }
    } else {  // mchunk == 7: 54272 valid bytes
        const char* xg = (const char*)(x + tbase);
        #pragma unroll
        for (int r = 0; r < 6; ++r) {
            int o = r * 8192 + tid * 16;
            __builtin_amdgcn_global_load_lds(
                (const __attribute__((address_space(1))) void*)(xg + o),
                (__attribute__((address_space(3))) void*)(As + o), 16, 0, 0);
        }
        if (tid < 320) {
            int o = 49152 + tid * 16;
            __builtin_amdgcn_global_load_lds(
                (const __attribute__((address_space(1))) void*)(xg + o),
                (__attribute__((address_space(3))) void*)(As + o), 16, 0, 0);
        }
    }

    // per-lane byte base into basis for this wave's 4 col-groups
    const char* bb = (const char*)Bt + (size_t)(wn * 4 * 64 + lane) * 16;
    bf16x8 B0[4], B1[4];
    auto loadPh = [&](int ph, bf16x8 (&dst)[4]) {
        const char* bp = bb + (size_t)ph * BPHB;
        #pragma unroll
        for (int nf = 0; nf < 4; ++nf)
            dst[nf] = *(const bf16x8*)(bp + nf * 1024);
    };
    loadPh(0, B0);

    asm volatile("s_waitcnt vmcnt(0)" ::: "memory");   // DMA + B0 landed
    __syncthreads();

    // ---- Step 2: reflect patches (LDS->LDS, disjoint read/write) ----
    if (mchunk == 0) {
        if (tid < 256) {
            float v = *(const float*)(As + (512 - tid) * 4);   // reads [1028,2048]
            *(float*)(As + tid * 4) = v;                       // writes [0,1024)
        }
        __syncthreads();
    } else if (mchunk == 7) {
        #pragma unroll
        for (int q = 0; q < 6; ++q) {
            int j = 13568 + q * 512 + tid;                     // 3072 elems
            float v = *(const float*)(As + (27134 - j) * 4);   // [41976,54266]
            *(float*)(As + j * 4) = v;                         // [54272,66560)
        }
        __syncthreads();
    }

    // ---- Step 3: convert sweep f32 -> bf16 (front 33KB, XOR-swizzled) ----
    {
        float fr[32];
        float fx[4];
        #pragma unroll
        for (int q = 0; q < 8; ++q) {
            f32x4 v = *(const f32x4*)(As + (q * 512 + tid) * 16);
            fr[q*4+0] = v[0]; fr[q*4+1] = v[1];
            fr[q*4+2] = v[2]; fr[q*4+3] = v[3];
        }
        if (tid < 64) {
            f32x4 v = *(const f32x4*)(As + (4096 + tid) * 16);
            fx[0] = v[0]; fx[1] = v[1]; fx[2] = v[2]; fx[3] = v[3];
        }
        __syncthreads();    // all f32 reads done before bf16 overwrites
        #pragma unroll
        for (int q = 0; q < 8; ++q) {
            unsigned short h[4];
            #pragma unroll
            for (int e = 0; e < 4; ++e) {
                __hip_bfloat16 t = __float2bfloat16(fr[q*4+e]);
                h[e] = *(unsigned short*)&t;
            }
            int a = (q * 512 + tid) * 8;
            a ^= ((a >> 9) & 7) << 4;
            *(u64*)(As + a) = (u64)h[0] | ((u64)h[1] << 16) |
                              ((u64)h[2] << 32) | ((u64)h[3] << 48);
        }
        if (tid < 64) {
            unsigned short h[4];
            #pragma unroll
            for (int e = 0; e < 4; ++e) {
                __hip_bfloat16 t = __float2bfloat16(fx[e]);
                h[e] = *(unsigned short*)&t;
            }
            int a = (4096 + tid) * 8;        // [32768,33280): swizzle identity
            *(u64*)(As + a) = (u64)h[0] | ((u64)h[1] << 16) |
                              ((u64)h[2] << 32) | ((u64)h[3] << 48);
        }
        __syncthreads();
    }

    f32x4 acc[4][4];
    #pragma unroll
    for (int i = 0; i < 4; ++i)
        #pragma unroll
        for (int j = 0; j < 4; ++j) acc[i][j] = 0;

    auto doPhase = [&](int ph, bf16x8 (&cur)[4]) {
        bf16x8 af[4];
        #pragma unroll
        for (int mf = 0; mf < 4; ++mf) {
            int a = (mf * 16 + ll) * 512 + ph * 64 + lq * 16;
            a ^= ((a >> 9) & 7) << 4;
            af[mf] = *(const bf16x8*)(As + a);
        }
        __builtin_amdgcn_s_setprio(1);
        #pragma unroll
        for (int mf = 0; mf < 4; ++mf)
            #pragma unroll
            for (int nf = 0; nf < 4; ++nf)
                acc[mf][nf] = __builtin_amdgcn_mfma_f32_16x16x32_bf16(
                    af[mf], cur[nf], acc[mf][nf], 0, 0, 0);
        __builtin_amdgcn_s_setprio(0);
    };

    #pragma unroll 1
    for (int pp2 = 0; pp2 < 8; ++pp2) {
        const int ph = pp2 * 2;
        loadPh(ph + 1, B1);                 // prefetch odd phase
        doPhase(ph, B0);                    // compute even phase
        if (pp2 < 7) loadPh(ph + 2, B0);    // prefetch next even phase
        doPhase(ph + 1, B1);                // compute odd phase
    }

    // ---- epilogue: power = re^2 + im^2, t-major fp16, packed u64 stores ----
    const int sb = s * 64 + b;
    _Float16* pbase = powo + (size_t)sb * FPOW * TP;
    #pragma unroll
    for (int mf = 0; mf < 4; ++mf) {
        const int rl0 = mchunk * 64 + mf * 16 + lq * 4;
        #pragma unroll
        for (int p = 0; p < 2; ++p) {
            f32x4 re = acc[mf][2 * p], im = acc[mf][2 * p + 1];
            int gbin = wn * 2 + p;
            int bin = gbin * 16 + ll;
            bool nyq = (gbin == 0) && (ll == 0);
            unsigned short hp[4], hn[4];
            #pragma unroll
            for (int j = 0; j < 4; ++j) {
                float pr = re[j] * re[j];
                float pi = im[j] * im[j];
                _Float16 hv = (_Float16)(nyq ? pr : (pr + pi));
                hp[j] = *(unsigned short*)&hv;
                _Float16 hw = (_Float16)pi;
                hn[j] = *(unsigned short*)&hw;
            }
            u64 pk = (u64)hp[0] | ((u64)hp[1] << 16) |
                     ((u64)hp[2] << 32) | ((u64)hp[3] << 48);
            *(u64*)(pbase + (size_t)bin * TP + rl0) = pk;
            if (nyq) {
                u64 pk2 = (u64)hn[0] | ((u64)hn[1] << 16) |
                          ((u64)hn[2] << 32) | ((u64)hn[3] << 48);
                *(u64*)(pbase + (size_t)256 * TP + rl0) = pk2;
            }
        }
    }
}

// ---- warm-up: vectorized fp16 loads, static indexing --------------------
template<int W>
__device__ __forceinline__ float warm_fixed(const _Float16* __restrict__ nrow,
                                            int base, float alpha, float oma) {
    h8 blk[W / 8];
    #pragma unroll
    for (int i = 0; i < W / 8; ++i)
        blk[i] = *(const h8*)(nrow + base + i * 8);
    float v = (float)blk[0][0];
    #pragma unroll
    for (int i = 1; i < W; ++i)
        v = fmaf(alpha, v, oma * (float)blk[i / 8][i % 8]);
    v = fmaf(alpha, v, oma * (float)nrow[base + W]);
    return v;
}

// ---- chunked IIR scan + SPP + MSE, t-major fp16 planes ------------------
__global__ __launch_bounds__(256, 4)
void spp_loss_kernel(const _Float16* __restrict__ noiseP,
                     const _Float16* __restrict__ noisyP,
                     const float* __restrict__ est,
                     float* __restrict__ out,
                     float alpha)
{
    const double XI = 31.622776601683793;
    const float RATIO = (float)(1.0 + XI);
    const float COEF  = (float)(XI / (1.0 + XI));
    const float INVN  = (float)(1.0 / ((double)B_SZ * NF * TFR));

    int tid = blockIdx.x * blockDim.x + threadIdx.x;
    int f   = tid % NF;
    int rem = tid / NF;
    int c   = rem & (NCH - 1);
    int b   = rem >> 4;

    float local = 0.f;
    if (b < B_SZ) {
        const int t0   = c * CHUNKT;
        const int tend = min(TFR, t0 + CHUNKT);
        const _Float16* nrow = noiseP + ((size_t)b * NF + f) * TP;
        const _Float16* yrow = noisyP + ((size_t)b * NF + f) * TP;
        const float* erow = est + ((size_t)b * NF + f) * TFR;
        const float oma = 1.f - alpha;

        float v;
        if (t0 == 0)            v = (float)nrow[0];
        else if (t0 == CHUNKT)  v = warm_fixed<32>(nrow, 0, alpha, oma);
        else                    v = warm_fixed<48>(nrow, t0 - 48, alpha, oma);

        h8 wn8[4], wy8[4];
        #pragma unroll
        for (int i = 0; i < 4; ++i) {
            wn8[i] = *(const h8*)(nrow + t0 + i * 8);
            wy8[i] = *(const h8*)(yrow + t0 + i * 8);
        }
        float last_n = (float)nrow[t0 + 32];
        float last_y = (float)yrow[t0 + 32];
        float qe[32];
        #pragma unroll
        for (int i = 0; i < 32; ++i)
            qe[i] = erow[min(t0 + 1 + i, TFR - 1)];

        {
            float np = (float)wy8[0][0];
            float e0 = erow[t0];
            float expo = -np / (v + EPS_F) * COEF;
            float spp  = 1.f / fmaf(RATIO, __expf(expo), 1.f);
            float d = e0 - spp;
            local = fmaf(d, d, local);
        }
        #pragma unroll
        for (int i = 0; i < 32; ++i) {
            int t = t0 + 1 + i;
            float nv = (i < 31) ? (float)wn8[(i + 1) / 8][(i + 1) % 8] : last_n;
            v = fmaf(alpha, v, oma * nv);
            if (t < tend) {
                float yv = (i < 31) ? (float)wy8[(i + 1) / 8][(i + 1) % 8] : last_y;
                float expo = -yv / (v + EPS_F) * COEF;
                float spp  = 1.f / fmaf(RATIO, __expf(expo), 1.f);
                float d = qe[i] - spp;
                local = fmaf(d, d, local);
            }
        }
    }

    for (int off = 32; off > 0; off >>= 1)
        local += __shfl_down(local, off);
    __shared__ float wsum[4];
    if ((threadIdx.x & 63) == 0) wsum[threadIdx.x >> 6] = local;
    __syncthreads();
    if (threadIdx.x == 0) {
        float ssum = (wsum[0] + wsum[1]) + (wsum[2] + wsum[3]);
        atomicAdd(out, ssum * INVN);
    }
}

extern "C" void kernel_launch(void* const* d_in, const int* in_sizes, int n_in,
                              void* d_out, int out_size, void* d_ws, size_t ws_size,
                              hipStream_t stream) {
    const float* est  = (const float*)d_in[0];   // spp_estimate (B,1,F,T)
    const float* sig  = (const float*)d_in[1];   // input_sig    (B,1,N)
    const float* intf = (const float*)d_in[2];   // interference (B,1,N)

    unsigned short* Bt = (unsigned short*)d_ws;                 // 512 KB basis
    _Float16* powp = (_Float16*)((char*)d_ws + (size_t)512 * 1024);

    hipLaunchKernelGGL(build_basis, dim3(512), dim3(256), 0, stream, Bt);
    hipMemsetAsync(d_out, 0, sizeof(float), stream);

    hipFuncSetAttribute((const void*)dft_gemm,
                        hipFuncAttributeMaxDynamicSharedMemorySize, ASEGB);
    dim3 gG(8, 64, 2);
    hipLaunchKernelGGL(dft_gemm, gG, dim3(512), ASEGB, stream,
                       sig, intf, Bt, powp);

    const double alpha_d = exp(-((double)256) / (16000.0 * 0.072));
    const _Float16* noiseP = powp;                            // sb 0..63
    const _Float16* noisyP = powp + (size_t)B_SZ * FPOW * TP; // sb 64..127
    dim3 gB((B_SZ * NCH * NF + 255) / 256);
    hipLaunchKernelGGL(spp_loss_kernel, gB, dim3(256), 0, stream,
                       noiseP, noisyP, est, (float*)d_out, (float)alpha_d);
}

// Round 25
// 74.519 us; speedup vs baseline: 1.3994x; 1.1404x over previous
//
#include <hip/hip_runtime.h>
#include <hip/hip_bf16.h>
#include <math.h>

typedef __attribute__((ext_vector_type(8))) short bf16x8;
typedef __attribute__((ext_vector_type(4))) float f32x4;
typedef __attribute__((ext_vector_type(8))) _Float16 h8;
typedef unsigned long long u64;

#define NSAMP  128000
#define TFR    501
#define TP     512         // padded t-stride of power planes
#define FPOW   257
#define NF     257
#define B_SZ   64
#define CHUNKT 32
#define NCH    16
#define EPS_F  1.1920928955078125e-07f

#define SEG    16640       // 64*256 + 256 samples per 64-frame chunk
#define RAWB   66560       // SEG * 4 bytes: raw f32 staging region
#define WOFF   66560       // window table offset in LDS (2 KB)
#define LDS_TOTAL 68608
#define BGRPB  131072      // basis per parity group: 8ph x 16colgrp x 1024B
#define BPHB2  16384       // basis per phase per group

// ---- folded basis [grp(2)][ph(8)][colgrp(16)][lane(64)][8 bf16] + wtab --
// (r22 mapping, HW-verified): grp0: bin=2*eo vs s_e (cc=16 dead-im hosts
// Nyquist (-1)^m); grp1: bin=2*eo+1 vs s_o. No window in basis.
__global__ __launch_bounds__(256)
void build_basis(unsigned short* __restrict__ Bt, float* __restrict__ wtab) {
    const int c = blockIdx.x;            // 0..511
    const int grp = c >> 8, cc = c & 255;
    const int eo = (cc >> 5) * 16 + (cc & 15);
    const int isIm = (cc >> 4) & 1;
    const int bin = grp ? (2 * eo + 1) : (2 * eo);
    const int m = threadIdx.x;           // 0..255
    float v;
    if (grp == 0 && cc == 16) {
        v = (m & 1) ? -1.f : 1.f;        // Nyquist basis vs s_e
    } else {
        int mm = (bin * m) & 511;
        float th = (float)mm * (float)(2.0 * M_PI / 512.0);
        v = isIm ? -sinf(th) : cosf(th);
    }
    __hip_bfloat16 h = __float2bfloat16(v);
    int ph = m >> 5, cg16 = cc >> 4;
    int lane = ((m >> 3) & 3) * 16 + (cc & 15);
    size_t idx = (((size_t)(grp * 8 + ph) * 16 + cg16) * 64 + lane) * 8 + (m & 7);
    Bt[idx] = *reinterpret_cast<unsigned short*>(&h);
    if (c == 0) {
        wtab[m]       = sinf((float)m * (float)(M_PI / 512.0));
        wtab[m + 256] = sinf((float)(m + 256) * (float)(M_PI / 512.0));
    }
}

// ---- MFMA DFT GEMM v25: f32 DMA -> in-LDS fold+window+convert -> K=256 --
// grid (8 mchunk, 64 b, 2 s) = 1024 blocks, block 512 (8 waves).
// Stage (r24-verbatim): raw f32 segment via global_load_lds, reflect via
// LDS->LDS patches. NEW sweep: two disjoint row-halves, each {read x-pairs
// to regs -> barrier -> windowed fold -> packed bf16 swizzled writes}.
// K-loop (r22-verbatim): 8 phases of K=32, waves 0..3 even bins / 4..7 odd,
// B from L2 regs, copy-free ping-pong. MFMA count HALF of r24.
__global__ __launch_bounds__(512)
void dft_gemm(const float* __restrict__ sig,
              const float* __restrict__ intf,
              const unsigned short* __restrict__ Bt,
              const float* __restrict__ wtab,
              _Float16* __restrict__ powo)
{
    extern __shared__ char As[];

    const int mchunk = blockIdx.x, b = blockIdx.y, s = blockIdx.z;
    const int tid = threadIdx.x, lane = tid & 63, wn = tid >> 6;  // 8 waves
    const int lq = lane >> 4, ll = lane & 15;
    const float* x = (s == 0 ? intf : sig) + (size_t)b * NSAMP;
    const int tbase = mchunk * 16384 - 256;

    // ---- Step 1: f32 DMA into LDS (linear), edge-clamped; + window table ---
    if (mchunk >= 1 && mchunk <= 6) {
        const char* xg = (const char*)(x + tbase);
        #pragma unroll
        for (int r = 0; r < 8; ++r) {
            int o = r * 8192 + tid * 16;
            __builtin_amdgcn_global_load_lds(
                (const __attribute__((address_space(1))) void*)(xg + o),
                (__attribute__((address_space(3))) void*)(As + o), 16, 0, 0);
        }
        if (tid < 64) {
            int o = 65536 + tid * 16;
            __builtin_amdgcn_global_load_lds(
                (const __attribute__((address_space(1))) void*)(xg + o),
                (__attribute__((address_space(3))) void*)(As + o), 16, 0, 0);
        }
    } else if (mchunk == 0) {
        const char* xg = (const char*)x;
        #pragma unroll
        for (int r = 0; r < 8; ++r) {
            int o = 1024 + r * 8192 + tid * 16;
            __builtin_amdgcn_global_load_lds(
                (const __attribute__((address_space(1))) void*)(xg + o - 1024),
                (__attribute__((address_space(3))) void*)(As + o), 16, 0, 0);
        }
    } else {  // mchunk == 7: 54272 valid bytes
        const char* xg = (const char*)(x + tbase);
        #pragma unroll
        for (int r = 0; r < 6; ++r) {
            int o = r * 8192 + tid * 16;
            __builtin_amdgcn_global_load_lds(
                (const __attribute__((address_space(1))) void*)(xg + o),
                (__attribute__((address_space(3))) void*)(As + o), 16, 0, 0);
        }
        if (tid < 320) {
            int o = 49152 + tid * 16;
            __builtin_amdgcn_global_load_lds(
                (const __attribute__((address_space(1))) void*)(xg + o),
                (__attribute__((address_space(3))) void*)(As + o), 16, 0, 0);
        }
    }
    if (tid < 128) {   // window table: 2 KB
        int o = tid * 16;
        __builtin_amdgcn_global_load_lds(
            (const __attribute__((address_space(1))) void*)((const char*)wtab + o),
            (__attribute__((address_space(3))) void*)(As + WOFF + o), 16, 0, 0);
    }

    // B0 prefetch (regs) overlaps the DMA
    const int grp = wn >> 2;            // 0: even bins (s_e), 1: odd (s_o)
    const int grpoff = grp * 512;
    const char* WB = (const char*)Bt + (size_t)grp * BGRPB
                   + (wn & 3) * 4096 + lane * 16;
    bf16x8 B0[4], B1[4];
    auto loadPh = [&](int ph, bf16x8 (&dst)[4]) {
        const char* bp = WB + (size_t)ph * BPHB2;
        #pragma unroll
        for (int nf = 0; nf < 4; ++nf)
            dst[nf] = *(const bf16x8*)(bp + nf * 1024);
    };
    loadPh(0, B0);

    asm volatile("s_waitcnt vmcnt(0)" ::: "memory");   // DMA + B0 landed
    __syncthreads();

    // ---- Step 2: reflect patches (LDS->LDS, disjoint) [r24-verbatim] ----
    if (mchunk == 0) {
        if (tid < 256) {
            float v = *(const float*)(As + (512 - tid) * 4);
            *(float*)(As + tid * 4) = v;
        }
        __syncthreads();
    } else if (mchunk == 7) {
        #pragma unroll
        for (int q = 0; q < 6; ++q) {
            int j = 13568 + q * 512 + tid;
            float v = *(const float*)(As + (27134 - j) * 4);
            *(float*)(As + j * 4) = v;
        }
        __syncthreads();
    }

    // ---- Step 3: fold+window+convert sweep (two disjoint halves) ----
    {
        const char* wt = As + WOFF;
        #pragma unroll 1
        for (int hh = 0; hh < 2; ++hh) {
            f32x4 xa[4], xb[4];
            #pragma unroll
            for (int i = 0; i < 4; ++i) {
                int qid = i * 512 + tid;
                int row = hh * 32 + (qid >> 6);
                int mq = qid & 63;
                int ra = row * 1024 + mq * 16;     // (row*256 + mq*4)*4
                xa[i] = *(const f32x4*)(As + ra);
                xb[i] = *(const f32x4*)(As + ra + 1024);
            }
            __syncthreads();    // all reads of this half done before overwrite
            #pragma unroll
            for (int i = 0; i < 4; ++i) {
                int qid = i * 512 + tid;
                int row = hh * 32 + (qid >> 6);
                int mq = qid & 63;
                f32x4 we = *(const f32x4*)(wt + mq * 16);
                f32x4 wo = *(const f32x4*)(wt + 1024 + mq * 16);
                unsigned short he[4], ho[4];
                #pragma unroll
                for (int e = 0; e < 4; ++e) {
                    float pa = xa[i][e] * we[e];
                    float pb = xb[i][e] * wo[e];
                    __hip_bfloat16 t0 = __float2bfloat16(pa + pb);
                    __hip_bfloat16 t1 = __float2bfloat16(pa - pb);
                    he[e] = *(unsigned short*)&t0;
                    ho[e] = *(unsigned short*)&t1;
                }
                int ae = row * 1024 + mq * 8;      // e half [0,512) of row
                int ao = ae + 512;                 // o half
                ae ^= ((ae >> 10) & 7) << 4;
                ao ^= ((ao >> 10) & 7) << 4;
                *(u64*)(As + ae) = (u64)he[0] | ((u64)he[1] << 16) |
                                   ((u64)he[2] << 32) | ((u64)he[3] << 48);
                *(u64*)(As + ao) = (u64)ho[0] | ((u64)ho[1] << 16) |
                                   ((u64)ho[2] << 32) | ((u64)ho[3] << 48);
            }
            // no barrier needed between halves: writes(h0)=[0,32K) disjoint
            // from reads(h1)=[32K,66.5K)
        }
        __syncthreads();
    }

    f32x4 acc[4][4];
    #pragma unroll
    for (int i = 0; i < 4; ++i)
        #pragma unroll
        for (int j = 0; j < 4; ++j) acc[i][j] = 0;

    auto doPhase = [&](int ph, bf16x8 (&cur)[4]) {
        bf16x8 af[4];
        #pragma unroll
        for (int mf = 0; mf < 4; ++mf) {
            int a = (mf * 16 + ll) * 1024 + grpoff + ph * 64 + lq * 16;
            a ^= ((a >> 10) & 7) << 4;
            af[mf] = *(const bf16x8*)(As + a);
        }
        __builtin_amdgcn_s_setprio(1);
        #pragma unroll
        for (int mf = 0; mf < 4; ++mf)
            #pragma unroll
            for (int nf = 0; nf < 4; ++nf)
                acc[mf][nf] = __builtin_amdgcn_mfma_f32_16x16x32_bf16(
                    af[mf], cur[nf], acc[mf][nf], 0, 0, 0);
        __builtin_amdgcn_s_setprio(0);
    };

    #pragma unroll 1
    for (int pp2 = 0; pp2 < 4; ++pp2) {
        const int ph = pp2 * 2;
        loadPh(ph + 1, B1);                 // prefetch odd phase
        doPhase(ph, B0);                    // compute even phase
        if (pp2 < 3) loadPh(ph + 2, B0);    // prefetch next even phase
        doPhase(ph + 1, B1);                // compute odd phase
    }

    // ---- epilogue [r22-verbatim]: power, t-major fp16, packed u64 ----
    const int sb = s * 64 + b;
    _Float16* pbase = powo + (size_t)sb * FPOW * TP;
    #pragma unroll
    for (int mf = 0; mf < 4; ++mf) {
        const int rl0 = mchunk * 64 + mf * 16 + lq * 4;
        #pragma unroll
        for (int p = 0; p < 2; ++p) {
            f32x4 re = acc[mf][2 * p], im = acc[mf][2 * p + 1];
            int gb = (wn & 3) * 2 + p;
            int eo = gb * 16 + ll;
            int bin = grp ? (2 * eo + 1) : (2 * eo);
            bool nyq = (grp == 0) && (gb == 0) && (ll == 0);
            unsigned short hp[4], hn[4];
            #pragma unroll
            for (int j = 0; j < 4; ++j) {
                float pr = re[j] * re[j];
                float pi = im[j] * im[j];
                _Float16 hv = (_Float16)(nyq ? pr : (pr + pi));
                hp[j] = *(unsigned short*)&hv;
                _Float16 hw = (_Float16)pi;
                hn[j] = *(unsigned short*)&hw;
            }
            u64 pk = (u64)hp[0] | ((u64)hp[1] << 16) |
                     ((u64)hp[2] << 32) | ((u64)hp[3] << 48);
            *(u64*)(pbase + (size_t)bin * TP + rl0) = pk;
            if (nyq) {
                u64 pk2 = (u64)hn[0] | ((u64)hn[1] << 16) |
                          ((u64)hn[2] << 32) | ((u64)hn[3] << 48);
                *(u64*)(pbase + (size_t)256 * TP + rl0) = pk2;
            }
        }
    }
}

// ---- warm-up: vectorized fp16 loads, static indexing --------------------
template<int W>
__device__ __forceinline__ float warm_fixed(const _Float16* __restrict__ nrow,
                                            int base, float alpha, float oma) {
    h8 blk[W / 8];
    #pragma unroll
    for (int i = 0; i < W / 8; ++i)
        blk[i] = *(const h8*)(nrow + base + i * 8);
    float v = (float)blk[0][0];
    #pragma unroll
    for (int i = 1; i < W; ++i)
        v = fmaf(alpha, v, oma * (float)blk[i / 8][i % 8]);
    v = fmaf(alpha, v, oma * (float)nrow[base + W]);
    return v;
}

// ---- chunked IIR scan + SPP + MSE, t-major fp16 planes ------------------
__global__ __launch_bounds__(256, 4)
void spp_loss_kernel(const _Float16* __restrict__ noiseP,
                     const _Float16* __restrict__ noisyP,
                     const float* __restrict__ est,
                     float* __restrict__ out,
                     float alpha)
{
    const double XI = 31.622776601683793;
    const float RATIO = (float)(1.0 + XI);
    const float COEF  = (float)(XI / (1.0 + XI));
    const float INVN  = (float)(1.0 / ((double)B_SZ * NF * TFR));

    int tid = blockIdx.x * blockDim.x + threadIdx.x;
    int f   = tid % NF;
    int rem = tid / NF;
    int c   = rem & (NCH - 1);
    int b   = rem >> 4;

    float local = 0.f;
    if (b < B_SZ) {
        const int t0   = c * CHUNKT;
        const int tend = min(TFR, t0 + CHUNKT);
        const _Float16* nrow = noiseP + ((size_t)b * NF + f) * TP;
        const _Float16* yrow = noisyP + ((size_t)b * NF + f) * TP;
        const float* erow = est + ((size_t)b * NF + f) * TFR;
        const float oma = 1.f - alpha;

        float v;
        if (t0 == 0)            v = (float)nrow[0];
        else if (t0 == CHUNKT)  v = warm_fixed<32>(nrow, 0, alpha, oma);
        else                    v = warm_fixed<48>(nrow, t0 - 48, alpha, oma);

        h8 wn8[4], wy8[4];
        #pragma unroll
        for (int i = 0; i < 4; ++i) {
            wn8[i] = *(const h8*)(nrow + t0 + i * 8);
            wy8[i] = *(const h8*)(yrow + t0 + i * 8);
        }
        float last_n = (float)nrow[t0 + 32];
        float last_y = (float)yrow[t0 + 32];
        float qe[32];
        #pragma unroll
        for (int i = 0; i < 32; ++i)
            qe[i] = erow[min(t0 + 1 + i, TFR - 1)];

        {
            float np = (float)wy8[0][0];
            float e0 = erow[t0];
            float expo = -np / (v + EPS_F) * COEF;
            float spp  = 1.f / fmaf(RATIO, __expf(expo), 1.f);
            float d = e0 - spp;
            local = fmaf(d, d, local);
        }
        #pragma unroll
        for (int i = 0; i < 32; ++i) {
            int t = t0 + 1 + i;
            float nv = (i < 31) ? (float)wn8[(i + 1) / 8][(i + 1) % 8] : last_n;
            v = fmaf(alpha, v, oma * nv);
            if (t < tend) {
                float yv = (i < 31) ? (float)wy8[(i + 1) / 8][(i + 1) % 8] : last_y;
                float expo = -yv / (v + EPS_F) * COEF;
                float spp  = 1.f / fmaf(RATIO, __expf(expo), 1.f);
                float d = qe[i] - spp;
                local = fmaf(d, d, local);
            }
        }
    }

    for (int off = 32; off > 0; off >>= 1)
        local += __shfl_down(local, off);
    __shared__ float wsum[4];
    if ((threadIdx.x & 63) == 0) wsum[threadIdx.x >> 6] = local;
    __syncthreads();
    if (threadIdx.x == 0) {
        float ssum = (wsum[0] + wsum[1]) + (wsum[2] + wsum[3]);
        atomicAdd(out, ssum * INVN);
    }
}

extern "C" void kernel_launch(void* const* d_in, const int* in_sizes, int n_in,
                              void* d_out, int out_size, void* d_ws, size_t ws_size,
                              hipStream_t stream) {
    const float* est  = (const float*)d_in[0];   // spp_estimate (B,1,F,T)
    const float* sig  = (const float*)d_in[1];   // input_sig    (B,1,N)
    const float* intf = (const float*)d_in[2];   // interference (B,1,N)

    unsigned short* Bt = (unsigned short*)d_ws;                       // 256 KB
    float* wtab = (float*)((char*)d_ws + (size_t)262144);             // 2 KB
    _Float16* powp = (_Float16*)((char*)d_ws + (size_t)512 * 1024);

    hipLaunchKernelGGL(build_basis, dim3(512), dim3(256), 0, stream, Bt, wtab);
    hipMemsetAsync(d_out, 0, sizeof(float), stream);

    hipFuncSetAttribute((const void*)dft_gemm,
                        hipFuncAttributeMaxDynamicSharedMemorySize, LDS_TOTAL);
    dim3 gG(8, 64, 2);
    hipLaunchKernelGGL(dft_gemm, gG, dim3(512), LDS_TOTAL, stream,
                       sig, intf, Bt, wtab, powp);

    const double alpha_d = exp(-((double)256) / (16000.0 * 0.072));
    const _Float16* noiseP = powp;                            // sb 0..63
    const _Float16* noisyP = powp + (size_t)B_SZ * FPOW * TP; // sb 64..127
    dim3 gB((B_SZ * NCH * NF + 255) / 256);
    hipLaunchKernelGGL(spp_loss_kernel, gB, dim3(256), 0, stream,
                       noiseP, noisyP, est, (float*)d_out, (float)alpha_d);
}

// Round 26
// 72.447 us; speedup vs baseline: 1.4394x; 1.0286x over previous
//
#include <hip/hip_runtime.h>
#include <hip/hip_bf16.h>
#include <math.h>

typedef __attribute__((ext_vector_type(8))) short bf16x8;
typedef __attribute__((ext_vector_type(4))) float f32x4;
typedef __attribute__((ext_vector_type(8))) _Float16 h8;
typedef unsigned long long u64;

#define NSAMP  128000
#define TFR    501
#define TP     512         // padded t-stride of power planes
#define FPOW   257
#define NF     257
#define B_SZ   64
#define CHUNKT 32
#define NCH    16
#define WARM   32          // alpha^32 ~ 8e-4: loss shift << threshold
#define EPS_F  1.1920928955078125e-07f

#define SEG    16640       // 64*256 + 256 samples per 64-frame chunk
#define WOFF   66560       // window table offset in LDS (2 KB)
#define LDS_TOTAL 68608
#define BGRPB  131072      // basis per parity group: 8ph x 16colgrp x 1024B
#define BPHB2  16384       // basis per phase per group

// ---- folded basis [grp(2)][ph(8)][colgrp(16)][lane(64)][8 bf16] + wtab --
// (r22/r25 mapping, HW-verified). Also zeroes d_out (replaces memset
// dispatch; same-stream ordering puts this before spp).
__global__ __launch_bounds__(256)
void build_basis(unsigned short* __restrict__ Bt, float* __restrict__ wtab,
                 float* __restrict__ out) {
    const int c = blockIdx.x;            // 0..511
    const int grp = c >> 8, cc = c & 255;
    const int eo = (cc >> 5) * 16 + (cc & 15);
    const int isIm = (cc >> 4) & 1;
    const int bin = grp ? (2 * eo + 1) : (2 * eo);
    const int m = threadIdx.x;           // 0..255
    float v;
    if (grp == 0 && cc == 16) {
        v = (m & 1) ? -1.f : 1.f;        // Nyquist basis vs s_e
    } else {
        int mm = (bin * m) & 511;
        float th = (float)mm * (float)(2.0 * M_PI / 512.0);
        v = isIm ? -sinf(th) : cosf(th);
    }
    __hip_bfloat16 h = __float2bfloat16(v);
    int ph = m >> 5, cg16 = cc >> 4;
    int lane = ((m >> 3) & 3) * 16 + (cc & 15);
    size_t idx = (((size_t)(grp * 8 + ph) * 16 + cg16) * 64 + lane) * 8 + (m & 7);
    Bt[idx] = *reinterpret_cast<unsigned short*>(&h);
    if (c == 0 && m < 2) {
        if (m == 0) *out = 0.f;
        wtab[m * 0 + threadIdx.x] = wtab[threadIdx.x];  // no-op placeholder
    }
    if (c == 0) {
        wtab[m]       = sinf((float)m * (float)(M_PI / 512.0));
        wtab[m + 256] = sinf((float)(m + 256) * (float)(M_PI / 512.0));
    }
}

// ---- MFMA DFT GEMM v25 (unchanged, the winner) --------------------------
__global__ __launch_bounds__(512)
void dft_gemm(const float* __restrict__ sig,
              const float* __restrict__ intf,
              const unsigned short* __restrict__ Bt,
              const float* __restrict__ wtab,
              _Float16* __restrict__ powo)
{
    extern __shared__ char As[];

    const int mchunk = blockIdx.x, b = blockIdx.y, s = blockIdx.z;
    const int tid = threadIdx.x, lane = tid & 63, wn = tid >> 6;  // 8 waves
    const int lq = lane >> 4, ll = lane & 15;
    const float* x = (s == 0 ? intf : sig) + (size_t)b * NSAMP;
    const int tbase = mchunk * 16384 - 256;

    // ---- Step 1: f32 DMA into LDS (linear), edge-clamped; + window table ---
    if (mchunk >= 1 && mchunk <= 6) {
        const char* xg = (const char*)(x + tbase);
        #pragma unroll
        for (int r = 0; r < 8; ++r) {
            int o = r * 8192 + tid * 16;
            __builtin_amdgcn_global_load_lds(
                (const __attribute__((address_space(1))) void*)(xg + o),
                (__attribute__((address_space(3))) void*)(As + o), 16, 0, 0);
        }
        if (tid < 64) {
            int o = 65536 + tid * 16;
            __builtin_amdgcn_global_load_lds(
                (const __attribute__((address_space(1))) void*)(xg + o),
                (__attribute__((address_space(3))) void*)(As + o), 16, 0, 0);
        }
    } else if (mchunk == 0) {
        const char* xg = (const char*)x;
        #pragma unroll
        for (int r = 0; r < 8; ++r) {
            int o = 1024 + r * 8192 + tid * 16;
            __builtin_amdgcn_global_load_lds(
                (const __attribute__((address_space(1))) void*)(xg + o - 1024),
                (__attribute__((address_space(3))) void*)(As + o), 16, 0, 0);
        }
    } else {  // mchunk == 7: 54272 valid bytes
        const char* xg = (const char*)(x + tbase);
        #pragma unroll
        for (int r = 0; r < 6; ++r) {
            int o = r * 8192 + tid * 16;
            __builtin_amdgcn_global_load_lds(
                (const __attribute__((address_space(1))) void*)(xg + o),
                (__attribute__((address_space(3))) void*)(As + o), 16, 0, 0);
        }
        if (tid < 320) {
            int o = 49152 + tid * 16;
            __builtin_amdgcn_global_load_lds(
                (const __attribute__((address_space(1))) void*)(xg + o),
                (__attribute__((address_space(3))) void*)(As + o), 16, 0, 0);
        }
    }
    if (tid < 128) {   // window table: 2 KB
        int o = tid * 16;
        __builtin_amdgcn_global_load_lds(
            (const __attribute__((address_space(1))) void*)((const char*)wtab + o),
            (__attribute__((address_space(3))) void*)(As + WOFF + o), 16, 0, 0);
    }

    const int grp = wn >> 2;            // 0: even bins (s_e), 1: odd (s_o)
    const int grpoff = grp * 512;
    const char* WB = (const char*)Bt + (size_t)grp * BGRPB
                   + (wn & 3) * 4096 + lane * 16;
    bf16x8 B0[4], B1[4];
    auto loadPh = [&](int ph, bf16x8 (&dst)[4]) {
        const char* bp = WB + (size_t)ph * BPHB2;
        #pragma unroll
        for (int nf = 0; nf < 4; ++nf)
            dst[nf] = *(const bf16x8*)(bp + nf * 1024);
    };
    loadPh(0, B0);

    asm volatile("s_waitcnt vmcnt(0)" ::: "memory");   // DMA + B0 landed
    __syncthreads();

    // ---- Step 2: reflect patches (LDS->LDS, disjoint) ----
    if (mchunk == 0) {
        if (tid < 256) {
            float v = *(const float*)(As + (512 - tid) * 4);
            *(float*)(As + tid * 4) = v;
        }
        __syncthreads();
    } else if (mchunk == 7) {
        #pragma unroll
        for (int q = 0; q < 6; ++q) {
            int j = 13568 + q * 512 + tid;
            float v = *(const float*)(As + (27134 - j) * 4);
            *(float*)(As + j * 4) = v;
        }
        __syncthreads();
    }

    // ---- Step 3: fold+window+convert sweep (two disjoint halves) ----
    {
        const char* wt = As + WOFF;
        #pragma unroll 1
        for (int hh = 0; hh < 2; ++hh) {
            f32x4 xa[4], xb[4];
            #pragma unroll
            for (int i = 0; i < 4; ++i) {
                int qid = i * 512 + tid;
                int row = hh * 32 + (qid >> 6);
                int mq = qid & 63;
                int ra = row * 1024 + mq * 16;
                xa[i] = *(const f32x4*)(As + ra);
                xb[i] = *(const f32x4*)(As + ra + 1024);
            }
            __syncthreads();
            #pragma unroll
            for (int i = 0; i < 4; ++i) {
                int qid = i * 512 + tid;
                int row = hh * 32 + (qid >> 6);
                int mq = qid & 63;
                f32x4 we = *(const f32x4*)(wt + mq * 16);
                f32x4 wo = *(const f32x4*)(wt + 1024 + mq * 16);
                unsigned short he[4], ho[4];
                #pragma unroll
                for (int e = 0; e < 4; ++e) {
                    float pa = xa[i][e] * we[e];
                    float pb = xb[i][e] * wo[e];
                    __hip_bfloat16 t0 = __float2bfloat16(pa + pb);
                    __hip_bfloat16 t1 = __float2bfloat16(pa - pb);
                    he[e] = *(unsigned short*)&t0;
                    ho[e] = *(unsigned short*)&t1;
                }
                int ae = row * 1024 + mq * 8;
                int ao = ae + 512;
                ae ^= ((ae >> 10) & 7) << 4;
                ao ^= ((ao >> 10) & 7) << 4;
                *(u64*)(As + ae) = (u64)he[0] | ((u64)he[1] << 16) |
                                   ((u64)he[2] << 32) | ((u64)he[3] << 48);
                *(u64*)(As + ao) = (u64)ho[0] | ((u64)ho[1] << 16) |
                                   ((u64)ho[2] << 32) | ((u64)ho[3] << 48);
            }
        }
        __syncthreads();
    }

    f32x4 acc[4][4];
    #pragma unroll
    for (int i = 0; i < 4; ++i)
        #pragma unroll
        for (int j = 0; j < 4; ++j) acc[i][j] = 0;

    auto doPhase = [&](int ph, bf16x8 (&cur)[4]) {
        bf16x8 af[4];
        #pragma unroll
        for (int mf = 0; mf < 4; ++mf) {
            int a = (mf * 16 + ll) * 1024 + grpoff + ph * 64 + lq * 16;
            a ^= ((a >> 10) & 7) << 4;
            af[mf] = *(const bf16x8*)(As + a);
        }
        __builtin_amdgcn_s_setprio(1);
        #pragma unroll
        for (int mf = 0; mf < 4; ++mf)
            #pragma unroll
            for (int nf = 0; nf < 4; ++nf)
                acc[mf][nf] = __builtin_amdgcn_mfma_f32_16x16x32_bf16(
                    af[mf], cur[nf], acc[mf][nf], 0, 0, 0);
        __builtin_amdgcn_s_setprio(0);
    };

    #pragma unroll 1
    for (int pp2 = 0; pp2 < 4; ++pp2) {
        const int ph = pp2 * 2;
        loadPh(ph + 1, B1);                 // prefetch odd phase
        doPhase(ph, B0);                    // compute even phase
        if (pp2 < 3) loadPh(ph + 2, B0);    // prefetch next even phase
        doPhase(ph + 1, B1);                // compute odd phase
    }

    // ---- epilogue: power, t-major fp16, packed u64 ----
    const int sb = s * 64 + b;
    _Float16* pbase = powo + (size_t)sb * FPOW * TP;
    #pragma unroll
    for (int mf = 0; mf < 4; ++mf) {
        const int rl0 = mchunk * 64 + mf * 16 + lq * 4;
        #pragma unroll
        for (int p = 0; p < 2; ++p) {
            f32x4 re = acc[mf][2 * p], im = acc[mf][2 * p + 1];
            int gb = (wn & 3) * 2 + p;
            int eo = gb * 16 + ll;
            int bin = grp ? (2 * eo + 1) : (2 * eo);
            bool nyq = (grp == 0) && (gb == 0) && (ll == 0);
            unsigned short hp[4], hn[4];
            #pragma unroll
            for (int j = 0; j < 4; ++j) {
                float pr = re[j] * re[j];
                float pi = im[j] * im[j];
                _Float16 hv = (_Float16)(nyq ? pr : (pr + pi));
                hp[j] = *(unsigned short*)&hv;
                _Float16 hw = (_Float16)pi;
                hn[j] = *(unsigned short*)&hw;
            }
            u64 pk = (u64)hp[0] | ((u64)hp[1] << 16) |
                     ((u64)hp[2] << 32) | ((u64)hp[3] << 48);
            *(u64*)(pbase + (size_t)bin * TP + rl0) = pk;
            if (nyq) {
                u64 pk2 = (u64)hn[0] | ((u64)hn[1] << 16) |
                          ((u64)hn[2] << 32) | ((u64)hn[3] << 48);
                *(u64*)(pbase + (size_t)256 * TP + rl0) = pk2;
            }
        }
    }
}

// ---- warm-up: vectorized fp16 loads, static indexing --------------------
template<int W>
__device__ __forceinline__ float warm_fixed(const _Float16* __restrict__ nrow,
                                            int base, float alpha, float oma) {
    h8 blk[W / 8];
    #pragma unroll
    for (int i = 0; i < W / 8; ++i)
        blk[i] = *(const h8*)(nrow + base + i * 8);
    float v = (float)blk[0][0];
    #pragma unroll
    for (int i = 1; i < W; ++i)
        v = fmaf(alpha, v, oma * (float)blk[i / 8][i % 8]);
    v = fmaf(alpha, v, oma * (float)nrow[base + W]);
    return v;
}

// ---- chunked IIR scan + SPP + MSE, t-major fp16 planes ------------------
__global__ __launch_bounds__(256, 4)
void spp_loss_kernel(const _Float16* __restrict__ noiseP,
                     const _Float16* __restrict__ noisyP,
                     const float* __restrict__ est,
                     float* __restrict__ out,
                     float alpha)
{
    const double XI = 31.622776601683793;
    const float RATIO = (float)(1.0 + XI);
    const float COEF  = (float)(XI / (1.0 + XI));
    const float INVN  = (float)(1.0 / ((double)B_SZ * NF * TFR));

    int tid = blockIdx.x * blockDim.x + threadIdx.x;
    int f   = tid % NF;
    int rem = tid / NF;
    int c   = rem & (NCH - 1);
    int b   = rem >> 4;

    float local = 0.f;
    if (b < B_SZ) {
        const int t0   = c * CHUNKT;
        const int tend = min(TFR, t0 + CHUNKT);
        const _Float16* nrow = noiseP + ((size_t)b * NF + f) * TP;
        const _Float16* yrow = noisyP + ((size_t)b * NF + f) * TP;
        const float* erow = est + ((size_t)b * NF + f) * TFR;
        const float oma = 1.f - alpha;

        float v;
        if (t0 == 0) v = (float)nrow[0];
        else         v = warm_fixed<WARM>(nrow, t0 - WARM, alpha, oma);

        h8 wn8[4], wy8[4];
        #pragma unroll
        for (int i = 0; i < 4; ++i) {
            wn8[i] = *(const h8*)(nrow + t0 + i * 8);
            wy8[i] = *(const h8*)(yrow + t0 + i * 8);
        }
        float last_n = (float)nrow[t0 + 32];
        float last_y = (float)yrow[t0 + 32];
        float qe[32];
        if (t0 + 33 <= TFR) {
            // vectorized est loads: contiguous, no clamp needed
            #pragma unroll
            for (int i = 0; i < 8; ++i) {
                float4 v4 = *(const float4*)(erow + t0 + 1 + i * 4);
                qe[i*4+0] = v4.x; qe[i*4+1] = v4.y;
                qe[i*4+2] = v4.z; qe[i*4+3] = v4.w;
            }
        } else {
            #pragma unroll
            for (int i = 0; i < 32; ++i)
                qe[i] = erow[min(t0 + 1 + i, TFR - 1)];
        }

        {
            float np = (float)wy8[0][0];
            float e0 = erow[t0];
            float expo = -np / (v + EPS_F) * COEF;
            float spp  = 1.f / fmaf(RATIO, __expf(expo), 1.f);
            float d = e0 - spp;
            local = fmaf(d, d, local);
        }
        #pragma unroll
        for (int i = 0; i < 32; ++i) {
            int t = t0 + 1 + i;
            float nv = (i < 31) ? (float)wn8[(i + 1) / 8][(i + 1) % 8] : last_n;
            v = fmaf(alpha, v, oma * nv);
            if (t < tend) {
                float yv = (i < 31) ? (float)wy8[(i + 1) / 8][(i + 1) % 8] : last_y;
                float expo = -yv / (v + EPS_F) * COEF;
                float spp  = 1.f / fmaf(RATIO, __expf(expo), 1.f);
                float d = qe[i] - spp;
                local = fmaf(d, d, local);
            }
        }
    }

    for (int off = 32; off > 0; off >>= 1)
        local += __shfl_down(local, off);
    __shared__ float wsum[4];
    if ((threadIdx.x & 63) == 0) wsum[threadIdx.x >> 6] = local;
    __syncthreads();
    if (threadIdx.x == 0) {
        float ssum = (wsum[0] + wsum[1]) + (wsum[2] + wsum[3]);
        atomicAdd(out, ssum * INVN);
    }
}

extern "C" void kernel_launch(void* const* d_in, const int* in_sizes, int n_in,
                              void* d_out, int out_size, void* d_ws, size_t ws_size,
                              hipStream_t stream) {
    const float* est  = (const float*)d_in[0];   // spp_estimate (B,1,F,T)
    const float* sig  = (const float*)d_in[1];   // input_sig    (B,1,N)
    const float* intf = (const float*)d_in[2];   // interference (B,1,N)

    unsigned short* Bt = (unsigned short*)d_ws;                       // 256 KB
    float* wtab = (float*)((char*)d_ws + (size_t)262144);             // 2 KB
    _Float16* powp = (_Float16*)((char*)d_ws + (size_t)512 * 1024);

    hipLaunchKernelGGL(build_basis, dim3(512), dim3(256), 0, stream,
                       Bt, wtab, (float*)d_out);

    hipFuncSetAttribute((const void*)dft_gemm,
                        hipFuncAttributeMaxDynamicSharedMemorySize, LDS_TOTAL);
    dim3 gG(8, 64, 2);
    hipLaunchKernelGGL(dft_gemm, gG, dim3(512), LDS_TOTAL, stream,
                       sig, intf, Bt, wtab, powp);

    const double alpha_d = exp(-((double)256) / (16000.0 * 0.072));
    const _Float16* noiseP = powp;                            // sb 0..63
    const _Float16* noisyP = powp + (size_t)B_SZ * FPOW * TP; // sb 64..127
    dim3 gB((B_SZ * NCH * NF + 255) / 256);
    hipLaunchKernelGGL(spp_loss_kernel, gB, dim3(256), 0, stream,
                       noiseP, noisyP, est, (float*)d_out, (float)alpha_d);
}

// Round 27
// 70.387 us; speedup vs baseline: 1.4816x; 1.0293x over previous
//
#include <hip/hip_runtime.h>
#include <hip/hip_bf16.h>
#include <math.h>

typedef __attribute__((ext_vector_type(8))) short bf16x8;
typedef __attribute__((ext_vector_type(4))) float f32x4;
typedef __attribute__((ext_vector_type(8))) _Float16 h8;
typedef unsigned long long u64;

#define NSAMP  128000
#define TFR    501
#define TP     512         // padded t-stride of power planes
#define FPOW   257
#define NF     257
#define B_SZ   64
#define CHUNKT 64
#define NCH    8
#define WARM   32          // alpha^32 ~ 8e-4: loss shift << threshold
#define EPS_F  1.1920928955078125e-07f

#define SEG    16640       // 64*256 + 256 samples per 64-frame chunk
#define WOFF   66560       // window table offset in LDS (2 KB)
#define LDS_TOTAL 68608
#define BGRPB  131072      // basis per parity group: 8ph x 16colgrp x 1024B
#define BPHB2  16384       // basis per phase per group

// ---- folded basis [grp(2)][ph(8)][colgrp(16)][lane(64)][8 bf16] + wtab --
// (r22/r25 mapping, HW-verified). Also zeroes d_out (replaces memset).
__global__ __launch_bounds__(256)
void build_basis(unsigned short* __restrict__ Bt, float* __restrict__ wtab,
                 float* __restrict__ out) {
    const int c = blockIdx.x;            // 0..511
    const int grp = c >> 8, cc = c & 255;
    const int eo = (cc >> 5) * 16 + (cc & 15);
    const int isIm = (cc >> 4) & 1;
    const int bin = grp ? (2 * eo + 1) : (2 * eo);
    const int m = threadIdx.x;           // 0..255
    float v;
    if (grp == 0 && cc == 16) {
        v = (m & 1) ? -1.f : 1.f;        // Nyquist basis vs s_e
    } else {
        int mm = (bin * m) & 511;
        float th = (float)mm * (float)(2.0 * M_PI / 512.0);
        v = isIm ? -sinf(th) : cosf(th);
    }
    __hip_bfloat16 h = __float2bfloat16(v);
    int ph = m >> 5, cg16 = cc >> 4;
    int lane = ((m >> 3) & 3) * 16 + (cc & 15);
    size_t idx = (((size_t)(grp * 8 + ph) * 16 + cg16) * 64 + lane) * 8 + (m & 7);
    Bt[idx] = *reinterpret_cast<unsigned short*>(&h);
    if (c == 0) {
        if (m == 0) *out = 0.f;
        wtab[m]       = sinf((float)m * (float)(M_PI / 512.0));
        wtab[m + 256] = sinf((float)(m + 256) * (float)(M_PI / 512.0));
    }
}

// ---- MFMA DFT GEMM v25 (frozen winner) ----------------------------------
__global__ __launch_bounds__(512)
void dft_gemm(const float* __restrict__ sig,
              const float* __restrict__ intf,
              const unsigned short* __restrict__ Bt,
              const float* __restrict__ wtab,
              _Float16* __restrict__ powo)
{
    extern __shared__ char As[];

    const int mchunk = blockIdx.x, b = blockIdx.y, s = blockIdx.z;
    const int tid = threadIdx.x, lane = tid & 63, wn = tid >> 6;  // 8 waves
    const int lq = lane >> 4, ll = lane & 15;
    const float* x = (s == 0 ? intf : sig) + (size_t)b * NSAMP;
    const int tbase = mchunk * 16384 - 256;

    // ---- Step 1: f32 DMA into LDS (linear), edge-clamped; + window table ---
    if (mchunk >= 1 && mchunk <= 6) {
        const char* xg = (const char*)(x + tbase);
        #pragma unroll
        for (int r = 0; r < 8; ++r) {
            int o = r * 8192 + tid * 16;
            __builtin_amdgcn_global_load_lds(
                (const __attribute__((address_space(1))) void*)(xg + o),
                (__attribute__((address_space(3))) void*)(As + o), 16, 0, 0);
        }
        if (tid < 64) {
            int o = 65536 + tid * 16;
            __builtin_amdgcn_global_load_lds(
                (const __attribute__((address_space(1))) void*)(xg + o),
                (__attribute__((address_space(3))) void*)(As + o), 16, 0, 0);
        }
    } else if (mchunk == 0) {
        const char* xg = (const char*)x;
        #pragma unroll
        for (int r = 0; r < 8; ++r) {
            int o = 1024 + r * 8192 + tid * 16;
            __builtin_amdgcn_global_load_lds(
                (const __attribute__((address_space(1))) void*)(xg + o - 1024),
                (__attribute__((address_space(3))) void*)(As + o), 16, 0, 0);
        }
    } else {  // mchunk == 7: 54272 valid bytes
        const char* xg = (const char*)(x + tbase);
        #pragma unroll
        for (int r = 0; r < 6; ++r) {
            int o = r * 8192 + tid * 16;
            __builtin_amdgcn_global_load_lds(
                (const __attribute__((address_space(1))) void*)(xg + o),
                (__attribute__((address_space(3))) void*)(As + o), 16, 0, 0);
        }
        if (tid < 320) {
            int o = 49152 + tid * 16;
            __builtin_amdgcn_global_load_lds(
                (const __attribute__((address_space(1))) void*)(xg + o),
                (__attribute__((address_space(3))) void*)(As + o), 16, 0, 0);
        }
    }
    if (tid < 128) {   // window table: 2 KB
        int o = tid * 16;
        __builtin_amdgcn_global_load_lds(
            (const __attribute__((address_space(1))) void*)((const char*)wtab + o),
            (__attribute__((address_space(3))) void*)(As + WOFF + o), 16, 0, 0);
    }

    const int grp = wn >> 2;            // 0: even bins (s_e), 1: odd (s_o)
    const int grpoff = grp * 512;
    const char* WB = (const char*)Bt + (size_t)grp * BGRPB
                   + (wn & 3) * 4096 + lane * 16;
    bf16x8 B0[4], B1[4];
    auto loadPh = [&](int ph, bf16x8 (&dst)[4]) {
        const char* bp = WB + (size_t)ph * BPHB2;
        #pragma unroll
        for (int nf = 0; nf < 4; ++nf)
            dst[nf] = *(const bf16x8*)(bp + nf * 1024);
    };
    loadPh(0, B0);

    asm volatile("s_waitcnt vmcnt(0)" ::: "memory");   // DMA + B0 landed
    __syncthreads();

    // ---- Step 2: reflect patches (LDS->LDS, disjoint) ----
    if (mchunk == 0) {
        if (tid < 256) {
            float v = *(const float*)(As + (512 - tid) * 4);
            *(float*)(As + tid * 4) = v;
        }
        __syncthreads();
    } else if (mchunk == 7) {
        #pragma unroll
        for (int q = 0; q < 6; ++q) {
            int j = 13568 + q * 512 + tid;
            float v = *(const float*)(As + (27134 - j) * 4);
            *(float*)(As + j * 4) = v;
        }
        __syncthreads();
    }

    // ---- Step 3: fold+window+convert sweep (two disjoint halves) ----
    {
        const char* wt = As + WOFF;
        #pragma unroll 1
        for (int hh = 0; hh < 2; ++hh) {
            f32x4 xa[4], xb[4];
            #pragma unroll
            for (int i = 0; i < 4; ++i) {
                int qid = i * 512 + tid;
                int row = hh * 32 + (qid >> 6);
                int mq = qid & 63;
                int ra = row * 1024 + mq * 16;
                xa[i] = *(const f32x4*)(As + ra);
                xb[i] = *(const f32x4*)(As + ra + 1024);
            }
            __syncthreads();
            #pragma unroll
            for (int i = 0; i < 4; ++i) {
                int qid = i * 512 + tid;
                int row = hh * 32 + (qid >> 6);
                int mq = qid & 63;
                f32x4 we = *(const f32x4*)(wt + mq * 16);
                f32x4 wo = *(const f32x4*)(wt + 1024 + mq * 16);
                unsigned short he[4], ho[4];
                #pragma unroll
                for (int e = 0; e < 4; ++e) {
                    float pa = xa[i][e] * we[e];
                    float pb = xb[i][e] * wo[e];
                    __hip_bfloat16 t0 = __float2bfloat16(pa + pb);
                    __hip_bfloat16 t1 = __float2bfloat16(pa - pb);
                    he[e] = *(unsigned short*)&t0;
                    ho[e] = *(unsigned short*)&t1;
                }
                int ae = row * 1024 + mq * 8;
                int ao = ae + 512;
                ae ^= ((ae >> 10) & 7) << 4;
                ao ^= ((ao >> 10) & 7) << 4;
                *(u64*)(As + ae) = (u64)he[0] | ((u64)he[1] << 16) |
                                   ((u64)he[2] << 32) | ((u64)he[3] << 48);
                *(u64*)(As + ao) = (u64)ho[0] | ((u64)ho[1] << 16) |
                                   ((u64)ho[2] << 32) | ((u64)ho[3] << 48);
            }
        }
        __syncthreads();
    }

    f32x4 acc[4][4];
    #pragma unroll
    for (int i = 0; i < 4; ++i)
        #pragma unroll
        for (int j = 0; j < 4; ++j) acc[i][j] = 0;

    auto doPhase = [&](int ph, bf16x8 (&cur)[4]) {
        bf16x8 af[4];
        #pragma unroll
        for (int mf = 0; mf < 4; ++mf) {
            int a = (mf * 16 + ll) * 1024 + grpoff + ph * 64 + lq * 16;
            a ^= ((a >> 10) & 7) << 4;
            af[mf] = *(const bf16x8*)(As + a);
        }
        __builtin_amdgcn_s_setprio(1);
        #pragma unroll
        for (int mf = 0; mf < 4; ++mf)
            #pragma unroll
            for (int nf = 0; nf < 4; ++nf)
                acc[mf][nf] = __builtin_amdgcn_mfma_f32_16x16x32_bf16(
                    af[mf], cur[nf], acc[mf][nf], 0, 0, 0);
        __builtin_amdgcn_s_setprio(0);
    };

    #pragma unroll 1
    for (int pp2 = 0; pp2 < 4; ++pp2) {
        const int ph = pp2 * 2;
        loadPh(ph + 1, B1);                 // prefetch odd phase
        doPhase(ph, B0);                    // compute even phase
        if (pp2 < 3) loadPh(ph + 2, B0);    // prefetch next even phase
        doPhase(ph + 1, B1);                // compute odd phase
    }

    // ---- epilogue: power, t-major fp16, packed u64 ----
    const int sb = s * 64 + b;
    _Float16* pbase = powo + (size_t)sb * FPOW * TP;
    #pragma unroll
    for (int mf = 0; mf < 4; ++mf) {
        const int rl0 = mchunk * 64 + mf * 16 + lq * 4;
        #pragma unroll
        for (int p = 0; p < 2; ++p) {
            f32x4 re = acc[mf][2 * p], im = acc[mf][2 * p + 1];
            int gb = (wn & 3) * 2 + p;
            int eo = gb * 16 + ll;
            int bin = grp ? (2 * eo + 1) : (2 * eo);
            bool nyq = (grp == 0) && (gb == 0) && (ll == 0);
            unsigned short hp[4], hn[4];
            #pragma unroll
            for (int j = 0; j < 4; ++j) {
                float pr = re[j] * re[j];
                float pi = im[j] * im[j];
                _Float16 hv = (_Float16)(nyq ? pr : (pr + pi));
                hp[j] = *(unsigned short*)&hv;
                _Float16 hw = (_Float16)pi;
                hn[j] = *(unsigned short*)&hw;
            }
            u64 pk = (u64)hp[0] | ((u64)hp[1] << 16) |
                     ((u64)hp[2] << 32) | ((u64)hp[3] << 48);
            *(u64*)(pbase + (size_t)bin * TP + rl0) = pk;
            if (nyq) {
                u64 pk2 = (u64)hn[0] | ((u64)hn[1] << 16) |
                          ((u64)hn[2] << 32) | ((u64)hn[3] << 48);
                *(u64*)(pbase + (size_t)256 * TP + rl0) = pk2;
            }
        }
    }
}

// ---- warm-up: vectorized fp16 loads, static indexing --------------------
template<int W>
__device__ __forceinline__ float warm_fixed(const _Float16* __restrict__ nrow,
                                            int base, float alpha, float oma) {
    h8 blk[W / 8];
    #pragma unroll
    for (int i = 0; i < W / 8; ++i)
        blk[i] = *(const h8*)(nrow + base + i * 8);
    float v = (float)blk[0][0];
    #pragma unroll
    for (int i = 1; i < W; ++i)
        v = fmaf(alpha, v, oma * (float)blk[i / 8][i % 8]);
    v = fmaf(alpha, v, oma * (float)nrow[base + W]);
    return v;
}

// ---- chunked IIR scan + SPP + MSE: CHUNKT=64, warm amortized 2x ---------
// Thread = (b, c, f); chunk of 64 t's as two 32-halves sharing one warm-up.
// v carries across halves: h0's 32nd update lands on var[t0+32] = h1 base.
__global__ __launch_bounds__(256, 4)
void spp_loss_kernel(const _Float16* __restrict__ noiseP,
                     const _Float16* __restrict__ noisyP,
                     const float* __restrict__ est,
                     float* __restrict__ out,
                     float alpha)
{
    const double XI = 31.622776601683793;
    const float RATIO = (float)(1.0 + XI);
    const float COEF  = (float)(XI / (1.0 + XI));
    const float INVN  = (float)(1.0 / ((double)B_SZ * NF * TFR));

    int tid = blockIdx.x * blockDim.x + threadIdx.x;
    int f   = tid % NF;
    int rem = tid / NF;
    int c   = rem & (NCH - 1);
    int b   = rem >> 3;

    float local = 0.f;
    if (b < B_SZ) {
        const int t0   = c * CHUNKT;
        const int tend = min(TFR, t0 + CHUNKT);
        const _Float16* nrow = noiseP + ((size_t)b * NF + f) * TP;
        const _Float16* yrow = noisyP + ((size_t)b * NF + f) * TP;
        const float* erow = est + ((size_t)b * NF + f) * TFR;
        const float oma = 1.f - alpha;

        float v;
        if (t0 == 0) v = (float)nrow[0];
        else         v = warm_fixed<WARM>(nrow, t0 - WARM, alpha, oma);

        #pragma unroll
        for (int h = 0; h < 2; ++h) {
            const int hb = t0 + h * 32;
            h8 wn8[4], wy8[4];
            #pragma unroll
            for (int i = 0; i < 4; ++i) {
                wn8[i] = *(const h8*)(nrow + hb + i * 8);
                wy8[i] = *(const h8*)(yrow + hb + i * 8);
            }
            float last_n = (float)nrow[hb + 32];
            float e0;
            float qe[31];
            if (hb + 33 <= TFR) {
                e0 = erow[hb];
                #pragma unroll
                for (int i = 0; i < 8; ++i) {
                    float4 v4 = *(const float4*)(erow + hb + 1 + i * 4);
                    if (i * 4 + 0 < 31) qe[i*4+0] = v4.x;
                    if (i * 4 + 1 < 31) qe[i*4+1] = v4.y;
                    if (i * 4 + 2 < 31) qe[i*4+2] = v4.z;
                    if (i * 4 + 3 < 31) qe[i*4+3] = v4.w;
                }
            } else {
                e0 = erow[min(hb, TFR - 1)];
                #pragma unroll
                for (int i = 0; i < 31; ++i)
                    qe[i] = erow[min(hb + 1 + i, TFR - 1)];
            }

            // base emit at hb (always < tend by construction)
            {
                float np = (float)wy8[0][0];
                float expo = -np / (v + EPS_F) * COEF;
                float spp  = 1.f / fmaf(RATIO, __expf(expo), 1.f);
                float d = e0 - spp;
                local = fmaf(d, d, local);
            }
            // updates hb+1 .. hb+32; emits hb+1 .. hb+31 (hb+32 is next base)
            #pragma unroll
            for (int i = 0; i < 32; ++i) {
                float nv = (i < 31) ? (float)wn8[(i + 1) / 8][(i + 1) % 8]
                                    : last_n;
                v = fmaf(alpha, v, oma * nv);
                if (i < 31) {
                    int t = hb + 1 + i;
                    if (t < tend) {
                        float yv = (float)wy8[(i + 1) / 8][(i + 1) % 8];
                        float expo = -yv / (v + EPS_F) * COEF;
                        float spp  = 1.f / fmaf(RATIO, __expf(expo), 1.f);
                        float d = qe[i] - spp;
                        local = fmaf(d, d, local);
                    }
                }
            }
        }
    }

    for (int off = 32; off > 0; off >>= 1)
        local += __shfl_down(local, off);
    __shared__ float wsum[4];
    if ((threadIdx.x & 63) == 0) wsum[threadIdx.x >> 6] = local;
    __syncthreads();
    if (threadIdx.x == 0) {
        float ssum = (wsum[0] + wsum[1]) + (wsum[2] + wsum[3]);
        atomicAdd(out, ssum * INVN);
    }
}

extern "C" void kernel_launch(void* const* d_in, const int* in_sizes, int n_in,
                              void* d_out, int out_size, void* d_ws, size_t ws_size,
                              hipStream_t stream) {
    const float* est  = (const float*)d_in[0];   // spp_estimate (B,1,F,T)
    const float* sig  = (const float*)d_in[1];   // input_sig    (B,1,N)
    const float* intf = (const float*)d_in[2];   // interference (B,1,N)

    unsigned short* Bt = (unsigned short*)d_ws;                       // 256 KB
    float* wtab = (float*)((char*)d_ws + (size_t)262144);             // 2 KB
    _Float16* powp = (_Float16*)((char*)d_ws + (size_t)512 * 1024);

    hipLaunchKernelGGL(build_basis, dim3(512), dim3(256), 0, stream,
                       Bt, wtab, (float*)d_out);

    hipFuncSetAttribute((const void*)dft_gemm,
                        hipFuncAttributeMaxDynamicSharedMemorySize, LDS_TOTAL);
    dim3 gG(8, 64, 2);
    hipLaunchKernelGGL(dft_gemm, gG, dim3(512), LDS_TOTAL, stream,
                       sig, intf, Bt, wtab, powp);

    const double alpha_d = exp(-((double)256) / (16000.0 * 0.072));
    const _Float16* noiseP = powp;                            // sb 0..63
    const _Float16* noisyP = powp + (size_t)B_SZ * FPOW * TP; // sb 64..127
    dim3 gB((B_SZ * NCH * NF + 255) / 256);
    hipLaunchKernelGGL(spp_loss_kernel, gB, dim3(256), 0, stream,
                       noiseP, noisyP, est, (float*)d_out, (float)alpha_d);
}